// Round 1
// baseline (6420.244 us; speedup 1.0000x reference)
//
#include <hip/hip_runtime.h>

#define PB 22
#define HB 64
#define EB 462
#define EPD 464
#define NL 5
#define HS 68
#define EPW 8
#define NGRP (EPD/EPW)

#define FOR8(M) M(0) M(1) M(2) M(3) M(4) M(5) M(6) M(7)

__device__ __forceinline__ float siluf(float x){ return x * (1.f/(1.f+__expf(-x))); }
__device__ __forceinline__ float sigf (float x){ return 1.f/(1.f+__expf(-x)); }
__device__ __forceinline__ float tanhff(float x){ float e=__expf(2.f*x); return 1.f - 2.f/(e+1.f); }

__device__ __forceinline__ float wsum64(float v){
  v += __shfl_xor(v,1);  v += __shfl_xor(v,2);  v += __shfl_xor(v,4);
  v += __shfl_xor(v,8);  v += __shfl_xor(v,16); v += __shfl_xor(v,32);
  return v;
}

// ---- per-edge-group macros (g = 0..7, textual; rely on locals eb, k, wv, lane) ----
#define EDGE_DECL(g) const int r##g = ser[eb+g]; const int c##g = sec[eb+g]; float acc##g;
#define EDGE_INIT(g) { \
    float d0 = sxc[r##g*3+0]-sxc[c##g*3+0]; \
    float d1 = sxc[r##g*3+1]-sxc[c##g*3+1]; \
    float d2 = sxc[r##g*3+2]-sxc[c##g*3+2]; \
    acc##g = fmaf(d0*d0+d1*d1+d2*d2, w128, fmaf(sea[eb+g], w129, be1v)); }
#define S1R(g) { const float4 h4 = *(const float4*)&sh[r##g*HS+k]; \
    acc##g=fmaf(h4.x,w0,acc##g); acc##g=fmaf(h4.y,w1,acc##g); \
    acc##g=fmaf(h4.z,w2,acc##g); acc##g=fmaf(h4.w,w3,acc##g); }
#define S1C(g) { const float4 h4 = *(const float4*)&sh[c##g*HS+k]; \
    acc##g=fmaf(h4.x,w0,acc##g); acc##g=fmaf(h4.y,w1,acc##g); \
    acc##g=fmaf(h4.z,w2,acc##g); acc##g=fmaf(h4.w,w3,acc##g); }
#define S1FIN(g) { sms[wv*EPW+g][lane] = siluf(acc##g); acc##g = be2v; }
#define S2R(g) { const float4 m4 = *(const float4*)&sms[wv*EPW+g][k]; \
    acc##g=fmaf(m4.x,w0,acc##g); acc##g=fmaf(m4.y,w1,acc##g); \
    acc##g=fmaf(m4.z,w2,acc##g); acc##g=fmaf(m4.w,w3,acc##g); }
#define S2FIN(g) float m##g = siluf(acc##g); \
    { float s = wsum64(m##g*wav)+bav; m##g *= sigf(s); sms[wv*EPW+g][lane] = m##g; acc##g = bc1v; }
#define S3FIN(g) float th##g; { float p = siluf(acc##g)*wc2v; th##g = tanhff(wsum64(p)); }
#define EWRITE(g) if (g < elim){ \
    atomicAdd(&sa[r##g*HS+lane], m##g); \
    if (lane < 3){ \
      float d = sxc[r##g*3+lane]-sxc[c##g*3+lane]; \
      atomicAdd(&sdx[r##g*3+lane], d*th##g); } }

__global__ __launch_bounds__(256, 3)
void egnn_block(const float* __restrict__ gt,  const float* __restrict__ gx,
                const float* __restrict__ gh0, const float* __restrict__ embW,
                const float* __restrict__ embB,
                const float* __restrict__ We1, const float* __restrict__ be1,
                const float* __restrict__ We2, const float* __restrict__ be2,
                const float* __restrict__ Wa,  const float* __restrict__ ba,
                const float* __restrict__ Wc1, const float* __restrict__ bc1,
                const float* __restrict__ Wc2,
                const float* __restrict__ Wn1, const float* __restrict__ bn1,
                const float* __restrict__ Wn2, const float* __restrict__ bn2,
                const int* __restrict__ rows,  const int* __restrict__ cols,
                float* __restrict__ out)
{
  const int b    = blockIdx.x;
  const int tid  = threadIdx.x;
  const int lane = tid & 63;
  const int wv   = tid >> 6;

  __shared__ __align__(16) float sh[PB*HS];
  __shared__ __align__(16) float sa[PB*HS];
  __shared__ __align__(16) float su[PB*HS];
  __shared__ float sxc[PB*3];
  __shared__ float sx0[PB*3];
  __shared__ float sdx[PB*3];
  __shared__ float sea[EPD];
  __shared__ int   ser[EPD];
  __shared__ int   sec[EPD];
  __shared__ __align__(16) float sms[4*EPW][HB];
  __shared__ float smean[3];

  const float tb = gt[b];

  for (int i = tid; i < PB*3; i += 256){ float v = gx[b*PB*3+i]; sx0[i]=v; sxc[i]=v; }
  for (int e = tid; e < EPD; e += 256){
    int r = 0, c = 1;
    if (e < EB){ r = rows[b*EB+e] - b*PB; c = cols[b*EB+e] - b*PB; }
    ser[e] = r; sec[e] = c;
  }
  // h = [onehot | t] @ emb_W + emb_b
  for (int i = tid; i < PB*HB; i += 256){
    int n = i >> 6, j = i & 63;
    float acc = embB[j] + tb*embW[PB*HB + j];
    #pragma unroll
    for (int k = 0; k < PB; k++) acc = fmaf(gh0[n*PB+k], embW[k*HB+j], acc);
    sh[n*HS+j] = acc;
  }
  __syncthreads();
  for (int e = tid; e < EPD; e += 256){
    int r = ser[e], c = sec[e];
    float d0 = sx0[r*3+0]-sx0[c*3+0];
    float d1 = sx0[r*3+1]-sx0[c*3+1];
    float d2 = sx0[r*3+2]-sx0[c*3+2];
    sea[e] = d0*d0 + d1*d1 + d2*d2;
  }
  __syncthreads();

  #pragma unroll 1
  for (int l = 0; l < NL; l++){
    for (int i = tid; i < PB*HS; i += 256) sa[i] = 0.f;
    for (int i = tid; i < PB*3;  i += 256) sdx[i] = 0.f;
    __syncthreads();

    const float* W1   = We1 + l*130*HB;
    const float* W2   = We2 + l*HB*HB;
    const float* Wc1l = Wc1 + l*HB*HB;
    const float be1v = be1[l*HB+lane];
    const float be2v = be2[l*HB+lane];
    const float bc1v = bc1[l*HB+lane];
    const float wav  = Wa [l*HB+lane];
    const float bav  = ba [l];
    const float wc2v = Wc2[l*HB+lane];
    const float w128 = W1[128*HB+lane];
    const float w129 = W1[129*HB+lane];

    #pragma unroll 1
    for (int grp = wv; grp < NGRP; grp += 4){
      const int eb = grp*EPW;
      FOR8(EDGE_DECL)
      FOR8(EDGE_INIT)
      #pragma unroll 4
      for (int k = 0; k < HB; k += 4){
        const float w0=W1[(k+0)*HB+lane], w1=W1[(k+1)*HB+lane],
                    w2=W1[(k+2)*HB+lane], w3=W1[(k+3)*HB+lane];
        FOR8(S1R)
      }
      #pragma unroll 4
      for (int k = 0; k < HB; k += 4){
        const float w0=W1[(HB+k+0)*HB+lane], w1=W1[(HB+k+1)*HB+lane],
                    w2=W1[(HB+k+2)*HB+lane], w3=W1[(HB+k+3)*HB+lane];
        FOR8(S1C)
      }
      FOR8(S1FIN)
      __builtin_amdgcn_wave_barrier();
      #pragma unroll 4
      for (int k = 0; k < HB; k += 4){
        const float w0=W2[(k+0)*HB+lane], w1=W2[(k+1)*HB+lane],
                    w2=W2[(k+2)*HB+lane], w3=W2[(k+3)*HB+lane];
        FOR8(S2R)
      }
      FOR8(S2FIN)
      __builtin_amdgcn_wave_barrier();
      #pragma unroll 4
      for (int k = 0; k < HB; k += 4){
        const float w0=Wc1l[(k+0)*HB+lane], w1=Wc1l[(k+1)*HB+lane],
                    w2=Wc1l[(k+2)*HB+lane], w3=Wc1l[(k+3)*HB+lane];
        FOR8(S2R)
      }
      FOR8(S3FIN)
      const int elim = EB - eb;
      FOR8(EWRITE)
    }
    __syncthreads();

    // apply coordinate update
    for (int i = tid; i < PB*3; i += 256) sxc[i] += sdx[i];

    // node MLP stage 1: u = silu([h, agg] @ Wn1 + bn1)
    const float* Wn1l = Wn1 + l*2*HB*HB;
    const float* Wn2l = Wn2 + l*HB*HB;
    for (int i = tid; i < PB*HB; i += 256){
      int n = i >> 6, j = i & 63;
      float acc = bn1[l*HB+j];
      #pragma unroll 4
      for (int k = 0; k < HB; k += 4){
        const float4 h4 = *(const float4*)&sh[n*HS+k];
        const float4 a4 = *(const float4*)&sa[n*HS+k];
        acc = fmaf(h4.x, Wn1l[(k+0)*HB+j], acc);
        acc = fmaf(h4.y, Wn1l[(k+1)*HB+j], acc);
        acc = fmaf(h4.z, Wn1l[(k+2)*HB+j], acc);
        acc = fmaf(h4.w, Wn1l[(k+3)*HB+j], acc);
        acc = fmaf(a4.x, Wn1l[(HB+k+0)*HB+j], acc);
        acc = fmaf(a4.y, Wn1l[(HB+k+1)*HB+j], acc);
        acc = fmaf(a4.z, Wn1l[(HB+k+2)*HB+j], acc);
        acc = fmaf(a4.w, Wn1l[(HB+k+3)*HB+j], acc);
      }
      su[n*HS+j] = siluf(acc);
    }
    __syncthreads();
    // node MLP stage 2: h += u @ Wn2 + bn2
    for (int i = tid; i < PB*HB; i += 256){
      int n = i >> 6, j = i & 63;
      float acc = bn2[l*HB+j];
      #pragma unroll 4
      for (int k = 0; k < HB; k += 4){
        const float4 u4 = *(const float4*)&su[n*HS+k];
        acc = fmaf(u4.x, Wn2l[(k+0)*HB+j], acc);
        acc = fmaf(u4.y, Wn2l[(k+1)*HB+j], acc);
        acc = fmaf(u4.z, Wn2l[(k+2)*HB+j], acc);
        acc = fmaf(u4.w, Wn2l[(k+3)*HB+j], acc);
      }
      sh[n*HS+j] += acc;
    }
    __syncthreads();
  }

  // vel = (xc - x0) with per-batch per-dim mean removed
  if (tid < 3){
    float s = 0.f;
    for (int p = 0; p < PB; p++) s += sxc[p*3+tid] - sx0[p*3+tid];
    smean[tid] = s * (1.f/PB);
  }
  __syncthreads();
  for (int i = tid; i < PB*3; i += 256){
    out[b*PB*3+i] = sxc[i] - sx0[i] - smean[i%3];
  }
}

extern "C" void kernel_launch(void* const* d_in, const int* in_sizes, int n_in,
                              void* d_out, int out_size, void* d_ws, size_t ws_size,
                              hipStream_t stream){
  const float* t    = (const float*)d_in[0];
  const float* x    = (const float*)d_in[1];
  const float* h0   = (const float*)d_in[2];
  const float* embW = (const float*)d_in[3];
  const float* embB = (const float*)d_in[4];
  const float* We1  = (const float*)d_in[5];
  const float* be1  = (const float*)d_in[6];
  const float* We2  = (const float*)d_in[7];
  const float* be2  = (const float*)d_in[8];
  const float* Wa   = (const float*)d_in[9];
  const float* ba   = (const float*)d_in[10];
  const float* Wc1  = (const float*)d_in[11];
  const float* bc1  = (const float*)d_in[12];
  const float* Wc2  = (const float*)d_in[13];
  const float* Wn1  = (const float*)d_in[14];
  const float* bn1  = (const float*)d_in[15];
  const float* Wn2  = (const float*)d_in[16];
  const float* bn2  = (const float*)d_in[17];
  const int* rows   = (const int*)d_in[18];
  const int* cols   = (const int*)d_in[19];

  hipLaunchKernelGGL(egnn_block, dim3(2048), dim3(256), 0, stream,
                     t, x, h0, embW, embB, We1, be1, We2, be2, Wa, ba,
                     Wc1, bc1, Wc2, Wn1, bn1, Wn2, bn2, rows, cols,
                     (float*)d_out);
}

// Round 3
// 3064.813 us; speedup vs baseline: 2.0948x; 2.0948x over previous
//
#include <hip/hip_runtime.h>

#define PB 22
#define HB 64
#define EB 462
#define NTIL 29
#define NL 5

// ws (shorts): hi tables then lo mirror at +WTOT
#define W1T_OFF  0        // [5][64][128]
#define W2T_OFF  40960    // [5][64][64]
#define WC1T_OFF 61440    // [5][64][64]
#define WN1T_OFF 81920    // [5][64][128]
#define WN2T_OFF 122880   // [5][64][64]
#define WTOT     143360

typedef __attribute__((ext_vector_type(8))) short short8v;
typedef __attribute__((ext_vector_type(4))) float f32x4;

#define MFMA16(a,b,c) __builtin_amdgcn_mfma_f32_16x16x32_bf16((a),(b),(c),0,0,0)

__device__ __forceinline__ short tobf(float f){
  unsigned u = __float_as_uint(f);
  return (short)((u + 0x7FFFu + ((u>>16)&1u)) >> 16);
}
__device__ __forceinline__ float bf2f(short h){
  return __uint_as_float(((unsigned)(unsigned short)h) << 16);
}
__device__ __forceinline__ void split2(float v, short &hi, short &lo){
  hi = tobf(v);
  lo = tobf(v - bf2f(hi));
}
__device__ __forceinline__ float siluf(float x){ return x/(1.f+__expf(-x)); }
__device__ __forceinline__ float sigf (float x){ return 1.f/(1.f+__expf(-x)); }
__device__ __forceinline__ float tanhff(float x){ float e=__expf(2.f*x); return 1.f-2.f/(e+1.f); }

__global__ void prep_weights(const float* __restrict__ We1, const float* __restrict__ We2,
                             const float* __restrict__ Wc1, const float* __restrict__ Wn1,
                             const float* __restrict__ Wn2, short* __restrict__ ws){
  int i = blockIdx.x*256 + threadIdx.x;
  if (i >= WTOT) return;
  float v;
  if (i < W2T_OFF){            int l=i>>13, r=i&8191, n=r>>7, k=r&127; v = We1[(l*130+k)*64+n]; }
  else if (i < WC1T_OFF){ int j=i-W2T_OFF;  int l=j>>12, r=j&4095, n=r>>6, k=r&63; v = We2[(l*64+k)*64+n]; }
  else if (i < WN1T_OFF){ int j=i-WC1T_OFF; int l=j>>12, r=j&4095, n=r>>6, k=r&63; v = Wc1[(l*64+k)*64+n]; }
  else if (i < WN2T_OFF){ int j=i-WN1T_OFF; int l=j>>13, r=j&8191, n=r>>7, k=r&127; v = Wn1[(l*128+k)*64+n]; }
  else {                  int j=i-WN2T_OFF; int l=j>>12, r=j&4095, n=r>>6, k=r&63; v = Wn2[(l*64+k)*64+n]; }
  short hi, lo;
  split2(v, hi, lo);
  ws[i] = hi; ws[WTOT+i] = lo;
}

__global__ __launch_bounds__(256, 2)
void egnn_mfma(const float* __restrict__ gt,  const float* __restrict__ gx,
               const float* __restrict__ gh0, const float* __restrict__ embW,
               const float* __restrict__ embB,
               const float* __restrict__ We1, const float* __restrict__ be1,
               const float* __restrict__ be2, const float* __restrict__ Wa,
               const float* __restrict__ ba,  const float* __restrict__ bc1,
               const float* __restrict__ Wc2, const float* __restrict__ bn1,
               const float* __restrict__ bn2,
               const int* __restrict__ rows,  const int* __restrict__ cols,
               const short* __restrict__ wbt, float* __restrict__ out)
{
  const int b    = blockIdx.x;
  const int tid  = threadIdx.x;
  const int lane = tid & 63;
  const int wv   = tid >> 6;
  const int c    = lane & 15;
  const int q    = lane >> 4;

  // hand-placed LDS pool (shorts), all frag bases 16B-aligned, strides 72/136
  __shared__ __align__(16) short sp[33472];
  __shared__ float saf[PB][66];
  __shared__ float sxc[66], sx0[66], sdx[66];
  __shared__ float smean[3];
  __shared__ short ser[464], sec[464];

  short* SHB_HI = sp;                    // [22][72] (reads may overrun rows<32: harmless)
  short* SHB_LO = sp + 1584;
  short* SAB_HI = sp + 3168;
  short* SAB_LO = sp + 4752;
  short* TW_HI  = sp + 6336 + wv*2304;   // per-wave [16][72]
  short* TW_LO  = TW_HI + 1152;
  short* WL     = sp + 15552;            // union: [64][136] @0, [64][72] @8704, [64][72] @13312

  const float tb = gt[b];

  for (int i = tid; i < 66; i += 256){ float v = gx[b*66+i]; sx0[i]=v; sxc[i]=v; }
  for (int e = tid; e < 464; e += 256){
    int r = 0, cc = 1;
    if (e < EB){ r = rows[b*EB+e] - b*PB; cc = cols[b*EB+e] - b*PB; }
    ser[e] = (short)r; sec[e] = (short)cc;
  }
  for (int i = tid; i < PB*HB; i += 256){
    int n = i >> 6, j = i & 63;
    float acc = embB[j] + tb*embW[PB*HB + j];
    #pragma unroll
    for (int k = 0; k < PB; k++) acc = fmaf(gh0[n*PB+k], embW[k*HB+j], acc);
    short hi, lo; split2(acc, hi, lo);
    SHB_HI[n*72+j] = hi; SHB_LO[n*72+j] = lo;
  }
  __syncthreads();

  #pragma unroll 1
  for (int l = 0; l < NL; l++){
    // ---- stage edge lo-weights into LDS union ----
    const short* gW1lo  = wbt + WTOT + W1T_OFF  + l*8192;
    const short* gW2lo  = wbt + WTOT + W2T_OFF  + l*4096;
    const short* gWC1lo = wbt + WTOT + WC1T_OFF + l*4096;
    for (int i = tid; i < 1024; i += 256){
      int col = i>>4, kc = i&15;
      *(short8v*)(WL + col*136 + kc*8) = *(const short8v*)(gW1lo + col*128 + kc*8);
    }
    for (int i = tid; i < 1024; i += 256){
      int h2 = i>>9, j = i&511, col = j>>3, kc = j&7;
      const short* src = h2 ? gWC1lo : gW2lo;
      *(short8v*)(WL + 8704 + h2*4608 + col*72 + kc*8) = *(const short8v*)(src + col*64 + kc*8);
    }
    for (int i = tid; i < PB*66; i += 256) ((float*)saf)[i] = 0.f;
    for (int i = tid; i < 66;    i += 256) sdx[i] = 0.f;

    // ---- per-lane scalars (f32) + hi-weight fragments in VGPRs ----
    float be1v[4], w128v[4], w129v[4], be2v[4], wavv[4], bc1v[4], wc2v[4];
    #pragma unroll
    for (int nt = 0; nt < 4; nt++){
      int col = nt*16 + c;
      be1v[nt]  = be1[l*HB+col];
      w128v[nt] = We1[(l*130+128)*HB+col];
      w129v[nt] = We1[(l*130+129)*HB+col];
      be2v[nt]  = be2[l*HB+col];
      wavv[nt]  = Wa [l*HB+col];
      bc1v[nt]  = bc1[l*HB+col];
      wc2v[nt]  = Wc2[l*HB+col];
    }
    const float bav = ba[l];

    short8v B1[4][4], B2[2][4], B3[2][4];
    #pragma unroll
    for (int nt = 0; nt < 4; nt++){
      int col = l*HB + nt*16 + c;
      #pragma unroll
      for (int kt = 0; kt < 4; kt++)
        B1[kt][nt] = *(const short8v*)(wbt + W1T_OFF + col*128 + kt*32 + q*8);
      #pragma unroll
      for (int kt = 0; kt < 2; kt++){
        B2[kt][nt] = *(const short8v*)(wbt + W2T_OFF  + col*64 + kt*32 + q*8);
        B3[kt][nt] = *(const short8v*)(wbt + WC1T_OFF + col*64 + kt*32 + q*8);
      }
    }
    __syncthreads();

    // ---- edge loop: 16-edge tiles ----
    #pragma unroll 1
    for (int t = wv; t < NTIL; t += 4){
      const int e0 = t*16;
      const int nA0 = ser[e0+c], nA1 = sec[e0+c];
      int nr_[4], nc_[4]; float rad_[4], ea_[4];
      #pragma unroll
      for (int r = 0; r < 4; r++){
        int e = e0 + q*4 + r;
        int rr = ser[e], cc = sec[e];
        nr_[r] = rr; nc_[r] = cc;
        float d0 = sxc[rr*3+0]-sxc[cc*3+0], d1 = sxc[rr*3+1]-sxc[cc*3+1], d2 = sxc[rr*3+2]-sxc[cc*3+2];
        rad_[r] = d0*d0 + d1*d1 + d2*d2;
        float g0 = sx0[rr*3+0]-sx0[cc*3+0], g1 = sx0[rr*3+1]-sx0[cc*3+1], g2 = sx0[rr*3+2]-sx0[cc*3+2];
        ea_[r]  = g0*g0 + g1*g1 + g2*g2;
      }
      // GEMM1 (3-term split)
      f32x4 acc1[4];
      #pragma unroll
      for (int nt = 0; nt < 4; nt++)
        #pragma unroll
        for (int r = 0; r < 4; r++)
          acc1[nt][r] = fmaf(rad_[r], w128v[nt], fmaf(ea_[r], w129v[nt], be1v[nt]));
      #pragma unroll
      for (int kt = 0; kt < 4; kt++){
        const int node = (kt < 2) ? nA0 : nA1;
        const int ko = (kt&1)*32 + q*8;
        short8v ah = *(const short8v*)(SHB_HI + node*72 + ko);
        short8v al = *(const short8v*)(SHB_LO + node*72 + ko);
        #pragma unroll
        for (int nt = 0; nt < 4; nt++){
          short8v bl = *(const short8v*)(WL + (nt*16+c)*136 + kt*32 + q*8);
          acc1[nt] = MFMA16(ah, B1[kt][nt], acc1[nt]);
          acc1[nt] = MFMA16(al, B1[kt][nt], acc1[nt]);
          acc1[nt] = MFMA16(ah, bl, acc1[nt]);
        }
      }
      __builtin_amdgcn_wave_barrier();
      #pragma unroll
      for (int nt = 0; nt < 4; nt++)
        #pragma unroll
        for (int r = 0; r < 4; r++){
          short hi, lo; split2(siluf(acc1[nt][r]), hi, lo);
          TW_HI[(q*4+r)*72 + nt*16+c] = hi;
          TW_LO[(q*4+r)*72 + nt*16+c] = lo;
        }
      __builtin_amdgcn_wave_barrier();
      short8v a0h = *(const short8v*)(TW_HI + c*72 + q*8);
      short8v a1h = *(const short8v*)(TW_HI + c*72 + 32 + q*8);
      short8v a0l = *(const short8v*)(TW_LO + c*72 + q*8);
      short8v a1l = *(const short8v*)(TW_LO + c*72 + 32 + q*8);
      // GEMM2 (3-term)
      f32x4 acc2[4];
      #pragma unroll
      for (int nt = 0; nt < 4; nt++){
        f32x4 a;
        #pragma unroll
        for (int r = 0; r < 4; r++) a[r] = be2v[nt];
        short8v bl0 = *(const short8v*)(WL + 8704 + (nt*16+c)*72 + q*8);
        short8v bl1 = *(const short8v*)(WL + 8704 + (nt*16+c)*72 + 32 + q*8);
        a = MFMA16(a0h, B2[0][nt], a);
        a = MFMA16(a0l, B2[0][nt], a);
        a = MFMA16(a0h, bl0, a);
        a = MFMA16(a1h, B2[1][nt], a);
        a = MFMA16(a1l, B2[1][nt], a);
        a = MFMA16(a1h, bl1, a);
        acc2[nt] = a;
      }
      // silu + attention gate (f32)
      float mg[4][4], part[4] = {0.f,0.f,0.f,0.f};
      #pragma unroll
      for (int nt = 0; nt < 4; nt++)
        #pragma unroll
        for (int r = 0; r < 4; r++){
          float mv = siluf(acc2[nt][r]); mg[nt][r] = mv;
          part[r] = fmaf(mv, wavv[nt], part[r]);
        }
      #pragma unroll
      for (int r = 0; r < 4; r++){
        float p = part[r];
        p += __shfl_xor(p,1); p += __shfl_xor(p,2); p += __shfl_xor(p,4); p += __shfl_xor(p,8);
        part[r] = sigf(p + bav);
      }
      #pragma unroll
      for (int nt = 0; nt < 4; nt++)
        #pragma unroll
        for (int r = 0; r < 4; r++) mg[nt][r] *= part[r];
      __builtin_amdgcn_wave_barrier();
      #pragma unroll
      for (int nt = 0; nt < 4; nt++)
        #pragma unroll
        for (int r = 0; r < 4; r++){
          short hi, lo; split2(mg[nt][r], hi, lo);
          TW_HI[(q*4+r)*72 + nt*16+c] = hi;
          TW_LO[(q*4+r)*72 + nt*16+c] = lo;
        }
      const int elim = EB - e0;
      #pragma unroll
      for (int r = 0; r < 4; r++)
        if (q*4+r < elim){
          #pragma unroll
          for (int nt = 0; nt < 4; nt++)
            atomicAdd(&saf[nr_[r]][nt*16+c], mg[nt][r]);
        }
      __builtin_amdgcn_wave_barrier();
      a0h = *(const short8v*)(TW_HI + c*72 + q*8);
      a1h = *(const short8v*)(TW_HI + c*72 + 32 + q*8);
      a0l = *(const short8v*)(TW_LO + c*72 + q*8);
      a1l = *(const short8v*)(TW_LO + c*72 + 32 + q*8);
      // GEMM3 (3-term)
      f32x4 acc3[4];
      #pragma unroll
      for (int nt = 0; nt < 4; nt++){
        f32x4 a;
        #pragma unroll
        for (int r = 0; r < 4; r++) a[r] = bc1v[nt];
        short8v bl0 = *(const short8v*)(WL + 13312 + (nt*16+c)*72 + q*8);
        short8v bl1 = *(const short8v*)(WL + 13312 + (nt*16+c)*72 + 32 + q*8);
        a = MFMA16(a0h, B3[0][nt], a);
        a = MFMA16(a0l, B3[0][nt], a);
        a = MFMA16(a0h, bl0, a);
        a = MFMA16(a1h, B3[1][nt], a);
        a = MFMA16(a1l, B3[1][nt], a);
        a = MFMA16(a1h, bl1, a);
        acc3[nt] = a;
      }
      float pp[4] = {0.f,0.f,0.f,0.f};
      #pragma unroll
      for (int nt = 0; nt < 4; nt++)
        #pragma unroll
        for (int r = 0; r < 4; r++)
          pp[r] = fmaf(siluf(acc3[nt][r]), wc2v[nt], pp[r]);
      #pragma unroll
      for (int r = 0; r < 4; r++){
        float p = pp[r];
        p += __shfl_xor(p,1); p += __shfl_xor(p,2); p += __shfl_xor(p,4); p += __shfl_xor(p,8);
        pp[r] = tanhff(p);
      }
      if (c < 3){
        #pragma unroll
        for (int r = 0; r < 4; r++)
          if (q*4+r < elim){
            float d = sxc[nr_[r]*3+c] - sxc[nc_[r]*3+c];
            atomicAdd(&sdx[nr_[r]*3+c], d*pp[r]);
          }
      }
    }
    __syncthreads();

    // ---- between phases: xc update, agg split, node lo-weight staging ----
    for (int i = tid; i < 66; i += 256) sxc[i] += sdx[i];
    for (int i = tid; i < PB*HB; i += 256){
      int n = i>>6, j = i&63;
      short hi, lo; split2(saf[n][j], hi, lo);
      SAB_HI[n*72+j] = hi; SAB_LO[n*72+j] = lo;
    }
    const short* gN1lo = wbt + WTOT + WN1T_OFF + l*8192;
    const short* gN2lo = wbt + WTOT + WN2T_OFF + l*4096;
    for (int i = tid; i < 1024; i += 256){
      int col = i>>4, kc = i&15;
      *(short8v*)(WL + col*136 + kc*8) = *(const short8v*)(gN1lo + col*128 + kc*8);
    }
    for (int i = tid; i < 512; i += 256){
      int col = i>>3, kc = i&7;
      *(short8v*)(WL + 8704 + col*72 + kc*8) = *(const short8v*)(gN2lo + col*64 + kc*8);
    }
    __syncthreads();

    // ---- node MLP: waves 0,1 each own a 16-row M-tile, full N=64 ----
    if (wv < 2){
      const int Mt = wv;
      float bn1v[4], bn2v[4];
      short8v Bn1[4][4], Bn2[2][4];
      #pragma unroll
      for (int nt = 0; nt < 4; nt++){
        int col = l*HB + nt*16 + c;
        bn1v[nt] = bn1[col]; bn2v[nt] = bn2[col];
        #pragma unroll
        for (int kt = 0; kt < 4; kt++)
          Bn1[kt][nt] = *(const short8v*)(wbt + WN1T_OFF + col*128 + kt*32 + q*8);
        #pragma unroll
        for (int kt = 0; kt < 2; kt++)
          Bn2[kt][nt] = *(const short8v*)(wbt + WN2T_OFF + col*64 + kt*32 + q*8);
      }
      f32x4 an[4];
      #pragma unroll
      for (int nt = 0; nt < 4; nt++){
        f32x4 a;
        #pragma unroll
        for (int r = 0; r < 4; r++) a[r] = bn1v[nt];
        an[nt] = a;
      }
      #pragma unroll
      for (int kt = 0; kt < 4; kt++){
        const short* bh = (kt < 2) ? SHB_HI : SAB_HI;
        const short* blp= (kt < 2) ? SHB_LO : SAB_LO;
        int ko = (kt&1)*32 + q*8;
        short8v ah = *(const short8v*)(bh  + (Mt*16+c)*72 + ko);
        short8v al = *(const short8v*)(blp + (Mt*16+c)*72 + ko);
        #pragma unroll
        for (int nt = 0; nt < 4; nt++){
          short8v bl = *(const short8v*)(WL + (nt*16+c)*136 + kt*32 + q*8);
          an[nt] = MFMA16(ah, Bn1[kt][nt], an[nt]);
          an[nt] = MFMA16(al, Bn1[kt][nt], an[nt]);
          an[nt] = MFMA16(ah, bl, an[nt]);
        }
      }
      __builtin_amdgcn_wave_barrier();
      #pragma unroll
      for (int nt = 0; nt < 4; nt++)
        #pragma unroll
        for (int r = 0; r < 4; r++){
          short hi, lo; split2(siluf(an[nt][r]), hi, lo);
          TW_HI[(q*4+r)*72 + nt*16+c] = hi;
          TW_LO[(q*4+r)*72 + nt*16+c] = lo;
        }
      __builtin_amdgcn_wave_barrier();
      short8v u0h = *(const short8v*)(TW_HI + c*72 + q*8);
      short8v u1h = *(const short8v*)(TW_HI + c*72 + 32 + q*8);
      short8v u0l = *(const short8v*)(TW_LO + c*72 + q*8);
      short8v u1l = *(const short8v*)(TW_LO + c*72 + 32 + q*8);
      f32x4 an2[4];
      #pragma unroll
      for (int nt = 0; nt < 4; nt++){
        f32x4 a;
        #pragma unroll
        for (int r = 0; r < 4; r++) a[r] = bn2v[nt];
        short8v bl0 = *(const short8v*)(WL + 8704 + (nt*16+c)*72 + q*8);
        short8v bl1 = *(const short8v*)(WL + 8704 + (nt*16+c)*72 + 32 + q*8);
        a = MFMA16(u0h, Bn2[0][nt], a);
        a = MFMA16(u0l, Bn2[0][nt], a);
        a = MFMA16(u0h, bl0, a);
        a = MFMA16(u1h, Bn2[1][nt], a);
        a = MFMA16(u1l, Bn2[1][nt], a);
        a = MFMA16(u1h, bl1, a);
        an2[nt] = a;
      }
      #pragma unroll
      for (int nt = 0; nt < 4; nt++)
        #pragma unroll
        for (int r = 0; r < 4; r++){
          int row = Mt*16 + q*4 + r;
          if (row < PB){
            int col = nt*16 + c;
            float hf = bf2f(SHB_HI[row*72+col]) + bf2f(SHB_LO[row*72+col]);
            float nh = hf + an2[nt][r];
            short hi, lo; split2(nh, hi, lo);
            SHB_HI[row*72+col] = hi; SHB_LO[row*72+col] = lo;
          }
        }
    }
    __syncthreads();
  }

  if (tid < 3){
    float s = 0.f;
    for (int p = 0; p < PB; p++) s += sxc[p*3+tid] - sx0[p*3+tid];
    smean[tid] = s * (1.f/PB);
  }
  __syncthreads();
  for (int i = tid; i < 66; i += 256)
    out[b*66+i] = sxc[i] - sx0[i] - smean[i%3];
}

extern "C" void kernel_launch(void* const* d_in, const int* in_sizes, int n_in,
                              void* d_out, int out_size, void* d_ws, size_t ws_size,
                              hipStream_t stream){
  const float* t    = (const float*)d_in[0];
  const float* x    = (const float*)d_in[1];
  const float* h0   = (const float*)d_in[2];
  const float* embW = (const float*)d_in[3];
  const float* embB = (const float*)d_in[4];
  const float* We1  = (const float*)d_in[5];
  const float* be1  = (const float*)d_in[6];
  const float* We2  = (const float*)d_in[7];
  const float* be2  = (const float*)d_in[8];
  const float* Wa   = (const float*)d_in[9];
  const float* ba   = (const float*)d_in[10];
  const float* Wc1  = (const float*)d_in[11];
  const float* bc1  = (const float*)d_in[12];
  const float* Wc2  = (const float*)d_in[13];
  const float* Wn1  = (const float*)d_in[14];
  const float* bn1  = (const float*)d_in[15];
  const float* Wn2  = (const float*)d_in[16];
  const float* bn2  = (const float*)d_in[17];
  const int* rows   = (const int*)d_in[18];
  const int* cols   = (const int*)d_in[19];
  short* wbt = (short*)d_ws;

  hipLaunchKernelGGL(prep_weights, dim3((WTOT+255)/256), dim3(256), 0, stream,
                     We1, We2, Wc1, Wn1, Wn2, wbt);
  hipLaunchKernelGGL(egnn_mfma, dim3(2048), dim3(256), 0, stream,
                     t, x, h0, embW, embB, We1, be1, be2, Wa, ba, bc1, Wc2,
                     bn1, bn2, rows, cols, (const short*)wbt, (float*)d_out);
}

// Round 4
// 2095.514 us; speedup vs baseline: 3.0638x; 1.4626x over previous
//
#include <hip/hip_runtime.h>

#define PB 22
#define HB 64
#define EB 462
#define NL 5

// ws (shorts): hi tables then lo mirror at +WTOT
#define W1T_OFF  0        // [5][64][128]  (We1 rows 0..127, col-major per n)
#define W2T_OFF  40960    // [5][64][64]
#define WC1T_OFF 61440    // [5][64][64]  K sigma-permuted
#define WN1T_OFF 81920    // [5][64][128]
#define WN2T_OFF 122880   // [5][64][64]
#define WTOT     143360

typedef __attribute__((ext_vector_type(8))) short short8v;
typedef __attribute__((ext_vector_type(4))) float f32x4;

#define MFMA16(a,b,c) __builtin_amdgcn_mfma_f32_16x16x32_bf16((a),(b),(c),0,0,0)

__device__ __forceinline__ short tobf(float f){
  unsigned u = __float_as_uint(f);
  return (short)((u + 0x7FFFu + ((u>>16)&1u)) >> 16);
}
__device__ __forceinline__ float bf2f(short h){
  return __uint_as_float(((unsigned)(unsigned short)h) << 16);
}
__device__ __forceinline__ void split2(float v, short &hi, short &lo){
  hi = tobf(v);
  lo = tobf(v - bf2f(hi));
}
__device__ __forceinline__ float siluf(float x){ return x/(1.f+__expf(-x)); }
__device__ __forceinline__ float sigf (float x){ return 1.f/(1.f+__expf(-x)); }
__device__ __forceinline__ float tanhff(float x){ float e=__expf(2.f*x); return 1.f-2.f/(e+1.f); }

__global__ void prep_weights(const float* __restrict__ We1, const float* __restrict__ We2,
                             const float* __restrict__ Wc1, const float* __restrict__ Wn1,
                             const float* __restrict__ Wn2, short* __restrict__ ws){
  int i = blockIdx.x*256 + threadIdx.x;
  if (i >= WTOT) return;
  float v;
  if (i < W2T_OFF){            int l=i>>13, r=i&8191, n=r>>7, k=r&127; v = We1[(l*130+k)*64+n]; }
  else if (i < WC1T_OFF){ int j=i-W2T_OFF;  int l=j>>12, r=j&4095, n=r>>6, k=r&63; v = We2[(l*64+k)*64+n]; }
  else if (i < WN1T_OFF){ int j=i-WC1T_OFF; int l=j>>12, r=j&4095, n=r>>6, k=r&63;
    // sigma: phys k = kt*32 + q*8 + j2*4.. -> logical h' = kt*32 + j2*16 + q*4 + j10
    int kk = (k>>5)*32 + ((k>>2)&1)*16 + ((k>>3)&3)*4 + (k&3);
    v = Wc1[(l*64+kk)*64+n]; }
  else if (i < WN2T_OFF){ int j=i-WN1T_OFF; int l=j>>13, r=j&8191, n=r>>7, k=r&127; v = Wn1[(l*128+k)*64+n]; }
  else {                  int j=i-WN2T_OFF; int l=j>>12, r=j&4095, n=r>>6, k=r&63; v = Wn2[(l*64+k)*64+n]; }
  short hi, lo;
  split2(v, hi, lo);
  ws[i] = hi; ws[WTOT+i] = lo;
}

#define M1J(idx, vv) { float s_ = siluf(vv); short h_, l_; split2(s_, h_, l_); mh[idx]=h_; ml[idx]=l_; }

__global__ __launch_bounds__(256, 2)
void egnn2(const float* __restrict__ gt,  const float* __restrict__ gx,
           const float* __restrict__ gh0, const float* __restrict__ embW,
           const float* __restrict__ embB,
           const float* __restrict__ We1, const float* __restrict__ be1,
           const float* __restrict__ be2, const float* __restrict__ Wa,
           const float* __restrict__ ba,  const float* __restrict__ bc1,
           const float* __restrict__ Wc2, const float* __restrict__ bn1,
           const float* __restrict__ bn2,
           const int* __restrict__ rows,  const int* __restrict__ cols,
           const short* __restrict__ wbt, float* __restrict__ out)
{
  const int b    = blockIdx.x;
  const int tid  = threadIdx.x;
  const int lane = tid & 63;
  const int wv   = tid >> 6;
  const int c    = lane & 15;
  const int q    = lane >> 4;

  __shared__ __align__(16) short SHB_HI[32*72];
  __shared__ __align__(16) short SHB_LO[32*72];
  __shared__ __align__(16) short WL2[64*72];      // W2-lo, per layer
  __shared__ __align__(16) float Y1s[22*68];
  __shared__ __align__(16) float Y2s[22*68];
  __shared__ __align__(16) float SAF[22*68];
  __shared__ __align__(16) unsigned UBs[22*68];   // packed {hi,lo} node hidden
  __shared__ float sxc[68], sx0[68], sdx[68];
  __shared__ float sea[464];
  __shared__ short ser[464], sec[464];
  __shared__ float smean[4];

  const float tb = gt[b];

  for (int i = tid; i < 66; i += 256){ float v = gx[b*66+i]; sx0[i]=v; sxc[i]=v; }
  for (int e = tid; e < 464; e += 256){
    int r = 0, cc = 1;
    if (e < EB){ r = rows[b*EB+e] - b*PB; cc = cols[b*EB+e] - b*PB; }
    ser[e] = (short)r; sec[e] = (short)cc;
  }
  for (int i = tid; i < PB*HB; i += 256){
    int n = i >> 6, j = i & 63;
    float acc = embB[j] + tb*embW[PB*HB + j];
    #pragma unroll
    for (int k = 0; k < PB; k++) acc = fmaf(gh0[n*PB+k], embW[k*HB+j], acc);
    short hi, lo; split2(acc, hi, lo);
    SHB_HI[n*72+j] = hi; SHB_LO[n*72+j] = lo;
  }
  __syncthreads();
  for (int e = tid; e < 464; e += 256){
    int r = ser[e], cc = sec[e];
    float d0 = sx0[r*3+0]-sx0[cc*3+0];
    float d1 = sx0[r*3+1]-sx0[cc*3+1];
    float d2 = sx0[r*3+2]-sx0[cc*3+2];
    sea[e] = d0*d0 + d1*d1 + d2*d2;
  }
  __syncthreads();

  #pragma unroll 1
  for (int l = 0; l < NL; l++){
    // ---------- phase A: zero accumulators, stage W2-lo, node GEMM Y1/Y2 ----------
    for (int i = tid; i < 22*68; i += 256) SAF[i] = 0.f;
    if (tid < 68) sdx[tid] = 0.f;
    { const short* gsrc = wbt + WTOT + W2T_OFF + l*4096;
      for (int i = tid; i < 512; i += 256){
        int col = i>>3, kc = i&7;
        *(short8v*)(WL2 + col*72 + kc*8) = *(const short8v*)(gsrc + col*64 + kc*8);
      } }
    #pragma unroll 1
    for (int task = wv; task < 16; task += 4){
      const int Yv = task>>3, Mt = (task>>2)&1, nt = task&3;
      const short* bp = wbt + W1T_OFF + (l*64 + nt*16 + c)*128 + Yv*64;
      const float initv = Yv ? 0.f : be1[l*64 + nt*16 + c];
      f32x4 acc = {initv, initv, initv, initv};
      #pragma unroll
      for (int kt = 0; kt < 2; kt++){
        short8v ah = *(const short8v*)(SHB_HI + (Mt*16+c)*72 + kt*32 + q*8);
        short8v al = *(const short8v*)(SHB_LO + (Mt*16+c)*72 + kt*32 + q*8);
        short8v bh = *(const short8v*)(bp + kt*32 + q*8);
        short8v bl = *(const short8v*)(bp + WTOT + kt*32 + q*8);
        acc = MFMA16(ah, bh, acc);
        acc = MFMA16(al, bh, acc);
        acc = MFMA16(ah, bl, acc);
      }
      float* Yp = Yv ? Y2s : Y1s;
      #pragma unroll
      for (int r = 0; r < 4; r++){
        int row = Mt*16 + q*4 + r;
        if (row < PB) Yp[row*68 + nt*16 + c] = acc[r];
      }
    }
    // ---------- per-layer register preloads ----------
    short8v W2h[2][4], C1h[2][4];
    #pragma unroll
    for (int nt = 0; nt < 4; nt++)
      #pragma unroll
      for (int kt = 0; kt < 2; kt++){
        W2h[kt][nt] = *(const short8v*)(wbt + W2T_OFF  + (l*64+nt*16+c)*64 + kt*32 + q*8);
        C1h[kt][nt] = *(const short8v*)(wbt + WC1T_OFF + (l*64+nt*16+c)*64 + kt*32 + q*8);
      }
    float4 w8a[2], w8b[2], w9a[2], w9b[2];
    #pragma unroll
    for (int kt = 0; kt < 2; kt++){
      const float* p8 = We1 + (l*130+128)*64 + kt*32 + q*8;
      const float* p9 = We1 + (l*130+129)*64 + kt*32 + q*8;
      w8a[kt] = *(const float4*)p8; w8b[kt] = *(const float4*)(p8+4);
      w9a[kt] = *(const float4*)p9; w9b[kt] = *(const float4*)(p9+4);
    }
    float be2v[4][4], bc1v[4][4], wavv[4][4], wc2v[4][4];
    #pragma unroll
    for (int nt = 0; nt < 4; nt++)
      #pragma unroll
      for (int r = 0; r < 4; r++){
        int hh = l*64 + nt*16 + q*4 + r;
        be2v[nt][r] = be2[hh]; bc1v[nt][r] = bc1[hh];
        wavv[nt][r] = Wa[hh];  wc2v[nt][r] = Wc2[hh];
      }
    const float bav = ba[l];
    __syncthreads();   // b1: Y/zero/WL2 ready

    // ---------- phase B: edge loop (barrier-free) ----------
    #pragma unroll 1
    for (int t = wv; t < 29; t += 4){
      const int e0 = t*16, elim = EB - e0;
      const int e = e0 + c;
      const int nr = ser[e], nc = sec[e];
      const float d0 = sxc[nr*3+0]-sxc[nc*3+0];
      const float d1 = sxc[nr*3+1]-sxc[nc*3+1];
      const float d2 = sxc[nr*3+2]-sxc[nc*3+2];
      const float rad = d0*d0 + d1*d1 + d2*d2;
      const float ea  = sea[e];
      // m1 = silu(Y1[nr] + Y2[nc] + rad*w128 + ea*w129), directly in frag layout
      short8v m1h[2], m1l[2];
      #pragma unroll
      for (int kt = 0; kt < 2; kt++){
        const float4 ya = *(const float4*)(Y1s + nr*68 + kt*32 + q*8);
        const float4 yb = *(const float4*)(Y1s + nr*68 + kt*32 + q*8 + 4);
        const float4 za = *(const float4*)(Y2s + nc*68 + kt*32 + q*8);
        const float4 zb = *(const float4*)(Y2s + nc*68 + kt*32 + q*8 + 4);
        float v0 = fmaf(rad,w8a[kt].x, fmaf(ea,w9a[kt].x, ya.x+za.x));
        float v1 = fmaf(rad,w8a[kt].y, fmaf(ea,w9a[kt].y, ya.y+za.y));
        float v2 = fmaf(rad,w8a[kt].z, fmaf(ea,w9a[kt].z, ya.z+za.z));
        float v3 = fmaf(rad,w8a[kt].w, fmaf(ea,w9a[kt].w, ya.w+za.w));
        float v4 = fmaf(rad,w8b[kt].x, fmaf(ea,w9b[kt].x, yb.x+zb.x));
        float v5 = fmaf(rad,w8b[kt].y, fmaf(ea,w9b[kt].y, yb.y+zb.y));
        float v6 = fmaf(rad,w8b[kt].z, fmaf(ea,w9b[kt].z, yb.z+zb.z));
        float v7 = fmaf(rad,w8b[kt].w, fmaf(ea,w9b[kt].w, yb.w+zb.w));
        short8v mh, ml;
        M1J(0,v0) M1J(1,v1) M1J(2,v2) M1J(3,v3)
        M1J(4,v4) M1J(5,v5) M1J(6,v6) M1J(7,v7)
        m1h[kt] = mh; m1l[kt] = ml;
      }
      // GEMM2 (swapped): D2^T[h'][edge], 3-term
      f32x4 acc2[4];
      #pragma unroll
      for (int nt = 0; nt < 4; nt++){
        f32x4 a; a[0]=be2v[nt][0]; a[1]=be2v[nt][1]; a[2]=be2v[nt][2]; a[3]=be2v[nt][3];
        acc2[nt] = a;
      }
      #pragma unroll
      for (int kt = 0; kt < 2; kt++)
        #pragma unroll
        for (int nt = 0; nt < 4; nt++){
          short8v w2l = *(const short8v*)(WL2 + (nt*16+c)*72 + kt*32 + q*8);
          acc2[nt] = MFMA16(W2h[kt][nt], m1h[kt], acc2[nt]);
          acc2[nt] = MFMA16(w2l,         m1h[kt], acc2[nt]);
          acc2[nt] = MFMA16(W2h[kt][nt], m1l[kt], acc2[nt]);
        }
      // silu + per-lane attention gate
      float m2[4][4]; float gp = 0.f;
      #pragma unroll
      for (int nt = 0; nt < 4; nt++)
        #pragma unroll
        for (int r = 0; r < 4; r++){
          float mv = siluf(acc2[nt][r]); m2[nt][r] = mv;
          gp = fmaf(mv, wavv[nt][r], gp);
        }
      gp += __shfl_xor(gp, 16); gp += __shfl_xor(gp, 32);
      const float gate = sigf(gp + bav);
      #pragma unroll
      for (int nt = 0; nt < 4; nt++)
        #pragma unroll
        for (int r = 0; r < 4; r++) m2[nt][r] *= gate;
      // aggregation (f32 atomics, exact)
      if (c < elim){
        #pragma unroll
        for (int nt = 0; nt < 4; nt++)
          #pragma unroll
          for (int r = 0; r < 4; r++)
            atomicAdd(&SAF[nr*68 + nt*16 + q*4 + r], m2[nt][r]);
      }
      // mg frags (slot->k via sigma, baked into WC1T prep)
      short8v mgh[2], mgl[2];
      #pragma unroll
      for (int kt = 0; kt < 2; kt++){
        short8v mh, ml;
        #pragma unroll
        for (int j = 0; j < 8; j++){
          short h_, l_; split2(m2[2*kt + (j>>2)][j&3], h_, l_);
          mh[j] = h_; ml[j] = l_;
        }
        mgh[kt] = mh; mgl[kt] = ml;
      }
      // GEMM3 (swapped, 2-term: Wc1-hi x {mg-hi, mg-lo})
      f32x4 acc3[4];
      #pragma unroll
      for (int nt = 0; nt < 4; nt++){
        f32x4 a; a[0]=bc1v[nt][0]; a[1]=bc1v[nt][1]; a[2]=bc1v[nt][2]; a[3]=bc1v[nt][3];
        acc3[nt] = a;
      }
      #pragma unroll
      for (int kt = 0; kt < 2; kt++)
        #pragma unroll
        for (int nt = 0; nt < 4; nt++){
          acc3[nt] = MFMA16(C1h[kt][nt], mgh[kt], acc3[nt]);
          acc3[nt] = MFMA16(C1h[kt][nt], mgl[kt], acc3[nt]);
        }
      float pp = 0.f;
      #pragma unroll
      for (int nt = 0; nt < 4; nt++)
        #pragma unroll
        for (int r = 0; r < 4; r++)
          pp = fmaf(siluf(acc3[nt][r]), wc2v[nt][r], pp);
      pp += __shfl_xor(pp, 16); pp += __shfl_xor(pp, 32);
      const float th = tanhff(pp);
      if (q == 0 && c < elim){
        atomicAdd(&sdx[nr*3+0], d0*th);
        atomicAdd(&sdx[nr*3+1], d1*th);
        atomicAdd(&sdx[nr*3+2], d2*th);
      }
    }
    __syncthreads();  // b2: edge atomics done

    // ---------- phase C: coord update + node MLP stage 1 ----------
    if (tid < 66) sxc[tid] += sdx[tid];
    {
      short8v An1h[4], An1l[4];
      #pragma unroll
      for (int kt = 0; kt < 4; kt++){
        const short* p = wbt + WN1T_OFF + (l*64 + wv*16 + c)*128 + kt*32 + q*8;
        An1h[kt] = *(const short8v*)p;
        An1l[kt] = *(const short8v*)(p + WTOT);
      }
      float bn1v[4];
      #pragma unroll
      for (int r = 0; r < 4; r++) bn1v[r] = bn1[l*64 + wv*16 + q*4 + r];
      #pragma unroll 1
      for (int tt = 0; tt < 2; tt++){
        const int node = tt*16 + c;
        const int nodeR = node < PB ? node : PB-1;
        f32x4 acc; acc[0]=bn1v[0]; acc[1]=bn1v[1]; acc[2]=bn1v[2]; acc[3]=bn1v[3];
        #pragma unroll
        for (int kt = 0; kt < 2; kt++){
          short8v bh = *(const short8v*)(SHB_HI + nodeR*72 + kt*32 + q*8);
          short8v bl = *(const short8v*)(SHB_LO + nodeR*72 + kt*32 + q*8);
          acc = MFMA16(An1h[kt], bh, acc);
          acc = MFMA16(An1l[kt], bh, acc);
          acc = MFMA16(An1h[kt], bl, acc);
        }
        #pragma unroll
        for (int kt = 2; kt < 4; kt++){
          const float4 fa = *(const float4*)(SAF + nodeR*68 + (kt-2)*32 + q*8);
          const float4 fb = *(const float4*)(SAF + nodeR*68 + (kt-2)*32 + q*8 + 4);
          short8v bh, bl; short h_, l_;
          split2(fa.x,h_,l_); bh[0]=h_; bl[0]=l_;
          split2(fa.y,h_,l_); bh[1]=h_; bl[1]=l_;
          split2(fa.z,h_,l_); bh[2]=h_; bl[2]=l_;
          split2(fa.w,h_,l_); bh[3]=h_; bl[3]=l_;
          split2(fb.x,h_,l_); bh[4]=h_; bl[4]=l_;
          split2(fb.y,h_,l_); bh[5]=h_; bl[5]=l_;
          split2(fb.z,h_,l_); bh[6]=h_; bl[6]=l_;
          split2(fb.w,h_,l_); bh[7]=h_; bl[7]=l_;
          acc = MFMA16(An1h[kt], bh, acc);
          acc = MFMA16(An1l[kt], bh, acc);
          acc = MFMA16(An1h[kt], bl, acc);
        }
        if (node < PB){
          #pragma unroll
          for (int r = 0; r < 4; r++){
            float s = siluf(acc[r]); short hi, lo; split2(s, hi, lo);
            UBs[node*68 + wv*16 + q*4 + r] =
              ((unsigned)(unsigned short)hi << 16) | (unsigned)(unsigned short)lo;
          }
        }
      }
    }
    __syncthreads();  // b3: u ready

    // ---------- phase D: node MLP stage 2 + h residual ----------
    {
      short8v An2h[2], An2l[2];
      #pragma unroll
      for (int kt = 0; kt < 2; kt++){
        const short* p = wbt + WN2T_OFF + (l*64 + wv*16 + c)*64 + kt*32 + q*8;
        An2h[kt] = *(const short8v*)p;
        An2l[kt] = *(const short8v*)(p + WTOT);
      }
      float bn2v[4];
      #pragma unroll
      for (int r = 0; r < 4; r++) bn2v[r] = bn2[l*64 + wv*16 + q*4 + r];
      #pragma unroll 1
      for (int tt = 0; tt < 2; tt++){
        const int node = tt*16 + c;
        const int nodeR = node < PB ? node : PB-1;
        f32x4 acc; acc[0]=bn2v[0]; acc[1]=bn2v[1]; acc[2]=bn2v[2]; acc[3]=bn2v[3];
        #pragma unroll
        for (int kt = 0; kt < 2; kt++){
          const uint4 da = *(const uint4*)(UBs + nodeR*68 + kt*32 + q*8);
          const uint4 db = *(const uint4*)(UBs + nodeR*68 + kt*32 + q*8 + 4);
          short8v bh, bl;
          bh[0]=(short)(da.x>>16); bl[0]=(short)(da.x&0xffffu);
          bh[1]=(short)(da.y>>16); bl[1]=(short)(da.y&0xffffu);
          bh[2]=(short)(da.z>>16); bl[2]=(short)(da.z&0xffffu);
          bh[3]=(short)(da.w>>16); bl[3]=(short)(da.w&0xffffu);
          bh[4]=(short)(db.x>>16); bl[4]=(short)(db.x&0xffffu);
          bh[5]=(short)(db.y>>16); bl[5]=(short)(db.y&0xffffu);
          bh[6]=(short)(db.z>>16); bl[6]=(short)(db.z&0xffffu);
          bh[7]=(short)(db.w>>16); bl[7]=(short)(db.w&0xffffu);
          acc = MFMA16(An2h[kt], bh, acc);
          acc = MFMA16(An2l[kt], bh, acc);
          acc = MFMA16(An2h[kt], bl, acc);
        }
        if (node < PB){
          #pragma unroll
          for (int r = 0; r < 4; r++){
            int idx = node*72 + wv*16 + q*4 + r;
            float old = bf2f(SHB_HI[idx]) + bf2f(SHB_LO[idx]);
            float nh = old + acc[r];
            short hi, lo; split2(nh, hi, lo);
            SHB_HI[idx] = hi; SHB_LO[idx] = lo;
          }
        }
      }
    }
    __syncthreads();  // b4: h updated
  }

  if (tid < 3){
    float s = 0.f;
    for (int p = 0; p < PB; p++) s += sxc[p*3+tid] - sx0[p*3+tid];
    smean[tid] = s * (1.f/PB);
  }
  __syncthreads();
  for (int i = tid; i < 66; i += 256)
    out[b*66+i] = sxc[i] - sx0[i] - smean[i%3];
}

extern "C" void kernel_launch(void* const* d_in, const int* in_sizes, int n_in,
                              void* d_out, int out_size, void* d_ws, size_t ws_size,
                              hipStream_t stream){
  const float* t    = (const float*)d_in[0];
  const float* x    = (const float*)d_in[1];
  const float* h0   = (const float*)d_in[2];
  const float* embW = (const float*)d_in[3];
  const float* embB = (const float*)d_in[4];
  const float* We1  = (const float*)d_in[5];
  const float* be1  = (const float*)d_in[6];
  const float* We2  = (const float*)d_in[7];
  const float* be2  = (const float*)d_in[8];
  const float* Wa   = (const float*)d_in[9];
  const float* ba   = (const float*)d_in[10];
  const float* Wc1  = (const float*)d_in[11];
  const float* bc1  = (const float*)d_in[12];
  const float* Wc2  = (const float*)d_in[13];
  const float* Wn1  = (const float*)d_in[14];
  const float* bn1  = (const float*)d_in[15];
  const float* Wn2  = (const float*)d_in[16];
  const float* bn2  = (const float*)d_in[17];
  const int* rows   = (const int*)d_in[18];
  const int* cols   = (const int*)d_in[19];
  short* wbt = (short*)d_ws;

  hipLaunchKernelGGL(prep_weights, dim3((WTOT+255)/256), dim3(256), 0, stream,
                     We1, We2, Wc1, Wn1, Wn2, wbt);
  hipLaunchKernelGGL(egnn2, dim3(2048), dim3(256), 0, stream,
                     t, x, h0, embW, embB, We1, be1, be2, Wa, ba, bc1, Wc2,
                     bn1, bn2, rows, cols, (const short*)wbt, (float*)d_out);
}

// Round 5
// 2027.184 us; speedup vs baseline: 3.1671x; 1.0337x over previous
//
#include <hip/hip_runtime.h>

#define PB 22
#define HB 64
#define EB 462
#define NL 5

// ws (shorts): hi tables then lo mirror at +WTOT
#define W1T_OFF  0        // [5][64][128]
#define W2T_OFF  40960    // [5][64][64]
#define WC1T_OFF 61440    // [5][64][64]  K sigma-permuted
#define WN1T_OFF 81920    // [5][64][128]
#define WN2T_OFF 122880   // [5][64][64]
#define WTOT     143360

typedef __attribute__((ext_vector_type(8))) short short8v;
typedef __attribute__((ext_vector_type(4))) float f32x4;

#define MFMA16(a,b,c) __builtin_amdgcn_mfma_f32_16x16x32_bf16((a),(b),(c),0,0,0)

__device__ __forceinline__ short tobf(float f){
  unsigned u = __float_as_uint(f);
  return (short)((u + 0x7FFFu + ((u>>16)&1u)) >> 16);
}
__device__ __forceinline__ float bf2f(short h){
  return __uint_as_float(((unsigned)(unsigned short)h) << 16);
}
__device__ __forceinline__ void split2(float v, short &hi, short &lo){
  hi = tobf(v);
  lo = tobf(v - bf2f(hi));
}
__device__ __forceinline__ float siluf(float x){ return x/(1.f+__expf(-x)); }
__device__ __forceinline__ float sigf (float x){ return 1.f/(1.f+__expf(-x)); }
__device__ __forceinline__ float tanhff(float x){ float e=__expf(2.f*x); return 1.f-2.f/(e+1.f); }

__global__ void prep_weights(const float* __restrict__ We1, const float* __restrict__ We2,
                             const float* __restrict__ Wc1, const float* __restrict__ Wn1,
                             const float* __restrict__ Wn2, short* __restrict__ ws){
  int i = blockIdx.x*256 + threadIdx.x;
  if (i >= WTOT) return;
  float v;
  if (i < W2T_OFF){            int l=i>>13, r=i&8191, n=r>>7, k=r&127; v = We1[(l*130+k)*64+n]; }
  else if (i < WC1T_OFF){ int j=i-W2T_OFF;  int l=j>>12, r=j&4095, n=r>>6, k=r&63; v = We2[(l*64+k)*64+n]; }
  else if (i < WN1T_OFF){ int j=i-WC1T_OFF; int l=j>>12, r=j&4095, n=r>>6, k=r&63;
    int kk = (k>>5)*32 + ((k>>2)&1)*16 + ((k>>3)&3)*4 + (k&3);
    v = Wc1[(l*64+kk)*64+n]; }
  else if (i < WN2T_OFF){ int j=i-WN1T_OFF; int l=j>>13, r=j&8191, n=r>>7, k=r&127; v = Wn1[(l*128+k)*64+n]; }
  else {                  int j=i-WN2T_OFF; int l=j>>12, r=j&4095, n=r>>6, k=r&63; v = Wn2[(l*64+k)*64+n]; }
  short hi, lo;
  split2(v, hi, lo);
  ws[i] = hi; ws[WTOT+i] = lo;
}

// ---- LDS pool byte offsets (all 16B aligned) ----
#define O_Y1   0        // float[22*68]; aliased: U_HI short[22*72]
#define O_Y2   5984     // float[22*68]; aliased: U_LO short[22*72]
#define O_SAF  11968    // float[22*68]
#define O_SHBH 17952    // short[22*72]
#define O_SHBL 21120    // short[22*72]
#define O_WL2  24288    // short[64*72]  W2-lo
#define O_WC1  33504    // short[64*72]  Wc1-hi
#define O_SCAL 42720    // float[384]: BE2@0 BC1@64 WA@128 WC2@192 W8@256 W9@320
#define O_SEA  44256    // float[464]
#define O_SXC  46112    // float[68]
#define O_SX0  46384
#define O_SDX  46656
#define O_SMEAN 46928   // float[4]
#define O_SER  46944    // uchar[464]
#define O_SEC  47408
#define POOLSZ 47872

__global__ __launch_bounds__(256, 2)
void egnn3(const float* __restrict__ gt,  const float* __restrict__ gx,
           const float* __restrict__ gh0, const float* __restrict__ embW,
           const float* __restrict__ embB,
           const float* __restrict__ We1, const float* __restrict__ be1,
           const float* __restrict__ be2, const float* __restrict__ Wa,
           const float* __restrict__ ba,  const float* __restrict__ bc1,
           const float* __restrict__ Wc2, const float* __restrict__ bn1,
           const float* __restrict__ bn2,
           const int* __restrict__ rows,  const int* __restrict__ cols,
           const short* __restrict__ wbt, float* __restrict__ out)
{
  const int b    = blockIdx.x;
  const int tid  = threadIdx.x;
  const int lane = tid & 63;
  const int wv   = tid >> 6;
  const int c    = lane & 15;
  const int q    = lane >> 4;

  __shared__ __align__(16) char pool[POOLSZ];
  float* Y1s   = (float*)(pool + O_Y1);
  float* Y2s   = (float*)(pool + O_Y2);
  float* SAF   = (float*)(pool + O_SAF);
  short* SHBH  = (short*)(pool + O_SHBH);
  short* SHBL  = (short*)(pool + O_SHBL);
  short* WL2   = (short*)(pool + O_WL2);
  short* WC1H  = (short*)(pool + O_WC1);
  float* SCALf = (float*)(pool + O_SCAL);
  float* sea   = (float*)(pool + O_SEA);
  float* sxc   = (float*)(pool + O_SXC);
  float* sx0   = (float*)(pool + O_SX0);
  float* sdx   = (float*)(pool + O_SDX);
  float* smean = (float*)(pool + O_SMEAN);
  unsigned char* SER = (unsigned char*)(pool + O_SER);
  unsigned char* SEC = (unsigned char*)(pool + O_SEC);
  short* UHI = (short*)(pool + O_Y1);   // alias, valid C..D phases
  short* ULO = (short*)(pool + O_Y2);

  const float tb = gt[b];

  for (int i = tid; i < 66; i += 256){ float v = gx[b*66+i]; sx0[i]=v; sxc[i]=v; }
  for (int e = tid; e < 464; e += 256){
    int r = 0, cc = 1;
    if (e < EB){ r = rows[b*EB+e] - b*PB; cc = cols[b*EB+e] - b*PB; }
    SER[e] = (unsigned char)r; SEC[e] = (unsigned char)cc;
  }
  for (int i = tid; i < PB*HB; i += 256){
    int n = i >> 6, j = i & 63;
    float acc = embB[j] + tb*embW[PB*HB + j];
    #pragma unroll
    for (int k = 0; k < PB; k++) acc = fmaf(gh0[n*PB+k], embW[k*HB+j], acc);
    short hi, lo; split2(acc, hi, lo);
    SHBH[n*72+j] = hi; SHBL[n*72+j] = lo;
  }
  __syncthreads();
  for (int e = tid; e < 464; e += 256){
    int r = SER[e], cc = SEC[e];
    float d0 = sx0[r*3+0]-sx0[cc*3+0];
    float d1 = sx0[r*3+1]-sx0[cc*3+1];
    float d2 = sx0[r*3+2]-sx0[cc*3+2];
    sea[e] = d0*d0 + d1*d1 + d2*d2;
  }
  __syncthreads();

  #pragma unroll 1
  for (int l = 0; l < NL; l++){
    // ---------- phase A ----------
    for (int i = tid; i < 22*68; i += 256) SAF[i] = 0.f;
    if (tid < 68) sdx[tid] = 0.f;
    if (tid < 64){
      SCALf[      tid] = be2[l*64+tid];
      SCALf[ 64 + tid] = bc1[l*64+tid];
      SCALf[128 + tid] = Wa [l*64+tid];
      SCALf[192 + tid] = Wc2[l*64+tid];
      SCALf[256 + tid] = We1[(l*130+128)*64+tid];
      SCALf[320 + tid] = We1[(l*130+129)*64+tid];
    }
    { const short* g2lo = wbt + WTOT + W2T_OFF + l*4096;
      const short* g1hi = wbt + WC1T_OFF + l*4096;
      for (int i = tid; i < 512; i += 256){
        int col = i>>3, kc = i&7;
        *(short8v*)(WL2  + col*72 + kc*8) = *(const short8v*)(g2lo + col*64 + kc*8);
        *(short8v*)(WC1H + col*72 + kc*8) = *(const short8v*)(g1hi + col*64 + kc*8);
      } }
    // node GEMM Y1/Y2 (16 tasks over 4 waves)
    #pragma unroll 1
    for (int task = wv; task < 16; task += 4){
      const int Yv = task>>3, Mt = (task>>2)&1, nt = task&3;
      const int arow = Mt*16 + c, arowR = arow < PB ? arow : PB-1;
      const short* bp = wbt + W1T_OFF + (l*64 + nt*16 + c)*128 + Yv*64;
      const float initv = Yv ? 0.f : be1[l*64 + nt*16 + c];
      f32x4 acc = {initv, initv, initv, initv};
      #pragma unroll
      for (int kt = 0; kt < 2; kt++){
        short8v ah = *(const short8v*)(SHBH + arowR*72 + kt*32 + q*8);
        short8v al = *(const short8v*)(SHBL + arowR*72 + kt*32 + q*8);
        short8v bh = *(const short8v*)(bp + kt*32 + q*8);
        short8v bl = *(const short8v*)(bp + WTOT + kt*32 + q*8);
        acc = MFMA16(ah, bh, acc);
        acc = MFMA16(al, bh, acc);
        acc = MFMA16(ah, bl, acc);
      }
      float* Yp = Yv ? Y2s : Y1s;
      #pragma unroll
      for (int r = 0; r < 4; r++){
        int row = Mt*16 + q*4 + r;
        if (row < PB) Yp[row*68 + nt*16 + c] = acc[r];
      }
    }
    // W2-hi fragments in registers (only persistent regs in edge loop)
    short8v W2h[2][4];
    #pragma unroll
    for (int nt = 0; nt < 4; nt++)
      #pragma unroll
      for (int kt = 0; kt < 2; kt++)
        W2h[kt][nt] = *(const short8v*)(wbt + W2T_OFF + (l*64+nt*16+c)*64 + kt*32 + q*8);
    const float bav = ba[l];
    __syncthreads();   // b1

    // ---------- phase B: edge loop ----------
    #pragma unroll 1
    for (int t = wv; t < 29; t += 4){
      const int e0 = t*16, elim = EB - e0;
      const int e = e0 + c;
      const int nr = SER[e], nc = SEC[e];
      const float d0 = sxc[nr*3+0]-sxc[nc*3+0];
      const float d1 = sxc[nr*3+1]-sxc[nc*3+1];
      const float d2 = sxc[nr*3+2]-sxc[nc*3+2];
      const float rad = d0*d0 + d1*d1 + d2*d2;
      const float ea  = sea[e];
      // m1 = silu(Y1[nr] + Y2[nc] + rad*w128 + ea*w129) in frag layout
      short8v m1h[2], m1l[2];
      #pragma unroll
      for (int kt = 0; kt < 2; kt++){
        const f32x4 w8a = *(const f32x4*)(SCALf+256 + kt*32 + q*8);
        const f32x4 w8b = *(const f32x4*)(SCALf+256 + kt*32 + q*8 + 4);
        const f32x4 w9a = *(const f32x4*)(SCALf+320 + kt*32 + q*8);
        const f32x4 w9b = *(const f32x4*)(SCALf+320 + kt*32 + q*8 + 4);
        const f32x4 ya = *(const f32x4*)(Y1s + nr*68 + kt*32 + q*8);
        const f32x4 yb = *(const f32x4*)(Y1s + nr*68 + kt*32 + q*8 + 4);
        const f32x4 za = *(const f32x4*)(Y2s + nc*68 + kt*32 + q*8);
        const f32x4 zb = *(const f32x4*)(Y2s + nc*68 + kt*32 + q*8 + 4);
        short8v mh, ml;
        #pragma unroll
        for (int j = 0; j < 4; j++){
          float v = fmaf(rad, w8a[j], fmaf(ea, w9a[j], ya[j]+za[j]));
          float s_ = siluf(v); short h_, l_; split2(s_, h_, l_);
          mh[j] = h_; ml[j] = l_;
        }
        #pragma unroll
        for (int j = 0; j < 4; j++){
          float v = fmaf(rad, w8b[j], fmaf(ea, w9b[j], yb[j]+zb[j]));
          float s_ = siluf(v); short h_, l_; split2(s_, h_, l_);
          mh[4+j] = h_; ml[4+j] = l_;
        }
        m1h[kt] = mh; m1l[kt] = ml;
      }
      // GEMM2 (swapped, 3-term)
      f32x4 acc2[4];
      #pragma unroll
      for (int nt = 0; nt < 4; nt++)
        acc2[nt] = *(const f32x4*)(SCALf + nt*16 + q*4);
      #pragma unroll
      for (int kt = 0; kt < 2; kt++)
        #pragma unroll
        for (int nt = 0; nt < 4; nt++){
          short8v w2l = *(const short8v*)(WL2 + (nt*16+c)*72 + kt*32 + q*8);
          acc2[nt] = MFMA16(W2h[kt][nt], m1h[kt], acc2[nt]);
          acc2[nt] = MFMA16(w2l,         m1h[kt], acc2[nt]);
          acc2[nt] = MFMA16(W2h[kt][nt], m1l[kt], acc2[nt]);
        }
      // silu + per-lane attention gate
      float m2[4][4]; float gp = 0.f;
      #pragma unroll
      for (int nt = 0; nt < 4; nt++){
        const f32x4 waq = *(const f32x4*)(SCALf+128 + nt*16 + q*4);
        #pragma unroll
        for (int r = 0; r < 4; r++){
          float mv = siluf(acc2[nt][r]); m2[nt][r] = mv;
          gp = fmaf(mv, waq[r], gp);
        }
      }
      gp += __shfl_xor(gp, 16); gp += __shfl_xor(gp, 32);
      const float gate = sigf(gp + bav);
      #pragma unroll
      for (int nt = 0; nt < 4; nt++)
        #pragma unroll
        for (int r = 0; r < 4; r++) m2[nt][r] *= gate;
      if (c < elim){
        #pragma unroll
        for (int nt = 0; nt < 4; nt++)
          #pragma unroll
          for (int r = 0; r < 4; r++)
            atomicAdd(&SAF[nr*68 + nt*16 + q*4 + r], m2[nt][r]);
      }
      // mg frags (sigma baked into WC1T prep)
      short8v mgh[2], mgl[2];
      #pragma unroll
      for (int kt = 0; kt < 2; kt++){
        short8v mh, ml;
        #pragma unroll
        for (int j = 0; j < 8; j++){
          short h_, l_; split2(m2[2*kt + (j>>2)][j&3], h_, l_);
          mh[j] = h_; ml[j] = l_;
        }
        mgh[kt] = mh; mgl[kt] = ml;
      }
      // GEMM3 (swapped, 2-term, Wc1-hi from LDS)
      f32x4 acc3[4];
      #pragma unroll
      for (int nt = 0; nt < 4; nt++)
        acc3[nt] = *(const f32x4*)(SCALf+64 + nt*16 + q*4);
      #pragma unroll
      for (int kt = 0; kt < 2; kt++)
        #pragma unroll
        for (int nt = 0; nt < 4; nt++){
          short8v c1 = *(const short8v*)(WC1H + (nt*16+c)*72 + kt*32 + q*8);
          acc3[nt] = MFMA16(c1, mgh[kt], acc3[nt]);
          acc3[nt] = MFMA16(c1, mgl[kt], acc3[nt]);
        }
      float pp = 0.f;
      #pragma unroll
      for (int nt = 0; nt < 4; nt++){
        const f32x4 wcq = *(const f32x4*)(SCALf+192 + nt*16 + q*4);
        #pragma unroll
        for (int r = 0; r < 4; r++)
          pp = fmaf(siluf(acc3[nt][r]), wcq[r], pp);
      }
      pp += __shfl_xor(pp, 16); pp += __shfl_xor(pp, 32);
      const float th = tanhff(pp);
      if (q == 0 && c < elim){
        atomicAdd(&sdx[nr*3+0], d0*th);
        atomicAdd(&sdx[nr*3+1], d1*th);
        atomicAdd(&sdx[nr*3+2], d2*th);
      }
    }
    __syncthreads();  // b2

    // ---------- phase C: coord update + node MLP stage 1 ----------
    if (tid < 66) sxc[tid] += sdx[tid];
    {
      short8v An1h[4], An1l[4];
      #pragma unroll
      for (int kt = 0; kt < 4; kt++){
        const short* p = wbt + WN1T_OFF + (l*64 + wv*16 + c)*128 + kt*32 + q*8;
        An1h[kt] = *(const short8v*)p;
        An1l[kt] = *(const short8v*)(p + WTOT);
      }
      float bn1v[4];
      #pragma unroll
      for (int r = 0; r < 4; r++) bn1v[r] = bn1[l*64 + wv*16 + q*4 + r];
      #pragma unroll 1
      for (int tt = 0; tt < 2; tt++){
        const int node = tt*16 + c;
        const int nodeR = node < PB ? node : PB-1;
        f32x4 acc; acc[0]=bn1v[0]; acc[1]=bn1v[1]; acc[2]=bn1v[2]; acc[3]=bn1v[3];
        #pragma unroll
        for (int kt = 0; kt < 2; kt++){
          short8v bh = *(const short8v*)(SHBH + nodeR*72 + kt*32 + q*8);
          short8v bl = *(const short8v*)(SHBL + nodeR*72 + kt*32 + q*8);
          acc = MFMA16(An1h[kt], bh, acc);
          acc = MFMA16(An1l[kt], bh, acc);
          acc = MFMA16(An1h[kt], bl, acc);
        }
        #pragma unroll
        for (int kt = 2; kt < 4; kt++){
          const f32x4 fa = *(const f32x4*)(SAF + nodeR*68 + (kt-2)*32 + q*8);
          const f32x4 fb = *(const f32x4*)(SAF + nodeR*68 + (kt-2)*32 + q*8 + 4);
          short8v bh, bl; short h_, l_;
          #pragma unroll
          for (int j = 0; j < 4; j++){ split2(fa[j],h_,l_); bh[j]=h_; bl[j]=l_; }
          #pragma unroll
          for (int j = 0; j < 4; j++){ split2(fb[j],h_,l_); bh[4+j]=h_; bl[4+j]=l_; }
          acc = MFMA16(An1h[kt], bh, acc);
          acc = MFMA16(An1l[kt], bh, acc);
          acc = MFMA16(An1h[kt], bl, acc);
        }
        if (node < PB){
          #pragma unroll
          for (int r = 0; r < 4; r++){
            float s = siluf(acc[r]); short hi, lo; split2(s, hi, lo);
            UHI[node*72 + wv*16 + q*4 + r] = hi;
            ULO[node*72 + wv*16 + q*4 + r] = lo;
          }
        }
      }
    }
    __syncthreads();  // b3

    // ---------- phase D: node MLP stage 2 + h residual ----------
    {
      short8v An2h[2], An2l[2];
      #pragma unroll
      for (int kt = 0; kt < 2; kt++){
        const short* p = wbt + WN2T_OFF + (l*64 + wv*16 + c)*64 + kt*32 + q*8;
        An2h[kt] = *(const short8v*)p;
        An2l[kt] = *(const short8v*)(p + WTOT);
      }
      float bn2v[4];
      #pragma unroll
      for (int r = 0; r < 4; r++) bn2v[r] = bn2[l*64 + wv*16 + q*4 + r];
      #pragma unroll 1
      for (int tt = 0; tt < 2; tt++){
        const int node = tt*16 + c;
        const int nodeR = node < PB ? node : PB-1;
        f32x4 acc; acc[0]=bn2v[0]; acc[1]=bn2v[1]; acc[2]=bn2v[2]; acc[3]=bn2v[3];
        #pragma unroll
        for (int kt = 0; kt < 2; kt++){
          short8v uh = *(const short8v*)(UHI + nodeR*72 + kt*32 + q*8);
          short8v ul = *(const short8v*)(ULO + nodeR*72 + kt*32 + q*8);
          acc = MFMA16(An2h[kt], uh, acc);
          acc = MFMA16(An2l[kt], uh, acc);
          acc = MFMA16(An2h[kt], ul, acc);
        }
        if (node < PB){
          #pragma unroll
          for (int r = 0; r < 4; r++){
            int idx = node*72 + wv*16 + q*4 + r;
            float old = bf2f(SHBH[idx]) + bf2f(SHBL[idx]);
            float nh = old + acc[r];
            short hi, lo; split2(nh, hi, lo);
            SHBH[idx] = hi; SHBL[idx] = lo;
          }
        }
      }
    }
    __syncthreads();  // b4
  }

  if (tid < 3){
    float s = 0.f;
    for (int p = 0; p < PB; p++) s += sxc[p*3+tid] - sx0[p*3+tid];
    smean[tid] = s * (1.f/PB);
  }
  __syncthreads();
  for (int i = tid; i < 66; i += 256)
    out[b*66+i] = sxc[i] - sx0[i] - smean[i%3];
}

extern "C" void kernel_launch(void* const* d_in, const int* in_sizes, int n_in,
                              void* d_out, int out_size, void* d_ws, size_t ws_size,
                              hipStream_t stream){
  const float* t    = (const float*)d_in[0];
  const float* x    = (const float*)d_in[1];
  const float* h0   = (const float*)d_in[2];
  const float* embW = (const float*)d_in[3];
  const float* embB = (const float*)d_in[4];
  const float* We1  = (const float*)d_in[5];
  const float* be1  = (const float*)d_in[6];
  const float* We2  = (const float*)d_in[7];
  const float* be2  = (const float*)d_in[8];
  const float* Wa   = (const float*)d_in[9];
  const float* ba   = (const float*)d_in[10];
  const float* Wc1  = (const float*)d_in[11];
  const float* bc1  = (const float*)d_in[12];
  const float* Wc2  = (const float*)d_in[13];
  const float* Wn1  = (const float*)d_in[14];
  const float* bn1  = (const float*)d_in[15];
  const float* Wn2  = (const float*)d_in[16];
  const float* bn2  = (const float*)d_in[17];
  const int* rows   = (const int*)d_in[18];
  const int* cols   = (const int*)d_in[19];
  short* wbt = (short*)d_ws;

  hipLaunchKernelGGL(prep_weights, dim3((WTOT+255)/256), dim3(256), 0, stream,
                     We1, We2, Wc1, Wn1, Wn2, wbt);
  hipLaunchKernelGGL(egnn3, dim3(2048), dim3(256), 0, stream,
                     t, x, h0, embW, embB, We1, be1, be2, Wa, ba, bc1, Wc2,
                     bn1, bn2, rows, cols, (const short*)wbt, (float*)d_out);
}

// Round 6
// 1926.338 us; speedup vs baseline: 3.3329x; 1.0524x over previous
//
#include <hip/hip_runtime.h>

#define PB 22
#define HB 64
#define EB 462
#define NL 5

// ws (shorts): hi tables then lo mirror at +WTOT
#define W1T_OFF  0        // [5][64][128]
#define W2T_OFF  40960    // [5][64][64]
#define WC1T_OFF 61440    // [5][64][64]  K sigma-permuted
#define WN1T_OFF 81920    // [5][64][128]
#define WN2T_OFF 122880   // [5][64][64]
#define WTOT     143360

typedef __attribute__((ext_vector_type(8))) short short8v;
typedef __attribute__((ext_vector_type(4))) float f32x4;

#define MFMA16(a,b,c) __builtin_amdgcn_mfma_f32_16x16x32_bf16((a),(b),(c),0,0,0)

__device__ __forceinline__ short tobf(float f){
  unsigned u = __float_as_uint(f);
  return (short)((u + 0x7FFFu + ((u>>16)&1u)) >> 16);   // RNE (prep only)
}
__device__ __forceinline__ float bf2f(short h){
  return __uint_as_float(((unsigned)(unsigned short)h) << 16);
}
__device__ __forceinline__ void split2(float v, short &hi, short &lo){  // prep: RNE
  hi = tobf(v);
  lo = tobf(v - bf2f(hi));
}
// cheap truncation split: err <= 2^-16 rel (hi trunc 2^-8, lo trunc 2^-8 of lo)
__device__ __forceinline__ void splitT(float v, short &hi, short &lo){
  unsigned u = __float_as_uint(v);
  hi = (short)(u >> 16);
  float lf = v - __uint_as_float(u & 0xFFFF0000u);
  lo = (short)(__float_as_uint(lf) >> 16);
}
__device__ __forceinline__ float siluf(float x){ return x/(1.f+__expf(-x)); }
__device__ __forceinline__ float sigf (float x){ return 1.f/(1.f+__expf(-x)); }
__device__ __forceinline__ float tanhff(float x){ float e=__expf(2.f*x); return 1.f-2.f/(e+1.f); }

__global__ void prep_weights(const float* __restrict__ We1, const float* __restrict__ We2,
                             const float* __restrict__ Wc1, const float* __restrict__ Wn1,
                             const float* __restrict__ Wn2, short* __restrict__ ws){
  int i = blockIdx.x*256 + threadIdx.x;
  if (i >= WTOT) return;
  float v;
  if (i < W2T_OFF){            int l=i>>13, r=i&8191, n=r>>7, k=r&127; v = We1[(l*130+k)*64+n]; }
  else if (i < WC1T_OFF){ int j=i-W2T_OFF;  int l=j>>12, r=j&4095, n=r>>6, k=r&63; v = We2[(l*64+k)*64+n]; }
  else if (i < WN1T_OFF){ int j=i-WC1T_OFF; int l=j>>12, r=j&4095, n=r>>6, k=r&63;
    int kk = (k>>5)*32 + ((k>>2)&1)*16 + ((k>>3)&3)*4 + (k&3);
    v = Wc1[(l*64+kk)*64+n]; }
  else if (i < WN2T_OFF){ int j=i-WN1T_OFF; int l=j>>13, r=j&8191, n=r>>7, k=r&127; v = Wn1[(l*128+k)*64+n]; }
  else {                  int j=i-WN2T_OFF; int l=j>>12, r=j&4095, n=r>>6, k=r&63; v = Wn2[(l*64+k)*64+n]; }
  short hi, lo;
  split2(v, hi, lo);
  ws[i] = hi; ws[WTOT+i] = lo;
}

// ---- LDS pool byte offsets (all 16B aligned) ----
#define O_Y1   0        // float[22*68]; aliased UHI short[22*72] in C/D
#define O_Y2   5984     // float[22*68]; aliased ULO
#define O_SAF  11968    // float[22*68]
#define O_SHBH 17952    // short[22*72]
#define O_SHBL 21120    // short[22*72]
#define O_WL2  24288    // short[64*72]  W2-lo
#define O_SCAL 33504    // float[384]: BE2@0 BC1@64 WA@128 WC2@192 W8@256 W9@320
#define O_SEA  35040    // float[464]
#define O_SXC  36896    // float[68]
#define O_SX0  37168
#define O_SDX  37440
#define O_SMEAN 37712   // float[4]
#define O_SER  37728    // uchar[464]
#define O_SEC  38192
#define POOLSZ 38656    // 38.7 KB -> 4 blocks/CU

__global__ __launch_bounds__(256, 4)
void egnn4(const float* __restrict__ gt,  const float* __restrict__ gx,
           const float* __restrict__ gh0, const float* __restrict__ embW,
           const float* __restrict__ embB,
           const float* __restrict__ We1, const float* __restrict__ be1,
           const float* __restrict__ be2, const float* __restrict__ Wa,
           const float* __restrict__ ba,  const float* __restrict__ bc1,
           const float* __restrict__ Wc2, const float* __restrict__ bn1,
           const float* __restrict__ bn2,
           const int* __restrict__ rows,  const int* __restrict__ cols,
           const short* __restrict__ wbt, float* __restrict__ out)
{
  const int b    = blockIdx.x;
  const int tid  = threadIdx.x;
  const int lane = tid & 63;
  const int wv   = tid >> 6;
  const int c    = lane & 15;
  const int q    = lane >> 4;

  __shared__ __align__(16) char pool[POOLSZ];
  float* Y1s   = (float*)(pool + O_Y1);
  float* Y2s   = (float*)(pool + O_Y2);
  float* SAF   = (float*)(pool + O_SAF);
  short* SHBH  = (short*)(pool + O_SHBH);
  short* SHBL  = (short*)(pool + O_SHBL);
  short* WL2   = (short*)(pool + O_WL2);
  float* SCALf = (float*)(pool + O_SCAL);
  float* sea   = (float*)(pool + O_SEA);
  float* sxc   = (float*)(pool + O_SXC);
  float* sx0   = (float*)(pool + O_SX0);
  float* sdx   = (float*)(pool + O_SDX);
  float* smean = (float*)(pool + O_SMEAN);
  unsigned char* SER = (unsigned char*)(pool + O_SER);
  unsigned char* SEC = (unsigned char*)(pool + O_SEC);
  short* UHI = (short*)(pool + O_Y1);
  short* ULO = (short*)(pool + O_Y2);

  const float tb = gt[b];

  for (int i = tid; i < 66; i += 256){ float v = gx[b*66+i]; sx0[i]=v; sxc[i]=v; }
  // permuted edge order: k-th slot = node (k%22)'s (k/22)-th incoming edge.
  // guarantees 16 consecutive slots hit 16 distinct dst nodes (atomics conflict-free).
  for (int k = tid; k < 464; k += 256){
    int kk = (k < EB) ? k : (k - EB);
    int n = kk % 22, s = kk / 22;
    int e;
    if (s < n) e = 2*(21*s - (s*(s-1))/2 + (n - s - 1)) + 1;
    else       e = 2*(21*n - (n*(n-1))/2 + (s - n));
    int r  = rows[b*EB+e] - b*PB;
    int c2 = cols[b*EB+e] - b*PB;
    SER[k] = (unsigned char)r; SEC[k] = (unsigned char)c2;
  }
  for (int i = tid; i < PB*HB; i += 256){
    int n = i >> 6, j = i & 63;
    float acc = embB[j] + tb*embW[PB*HB + j];
    #pragma unroll
    for (int k = 0; k < PB; k++) acc = fmaf(gh0[n*PB+k], embW[k*HB+j], acc);
    short hi, lo; splitT(acc, hi, lo);
    SHBH[n*72+j] = hi; SHBL[n*72+j] = lo;
  }
  __syncthreads();
  for (int e = tid; e < 464; e += 256){
    int r = SER[e], cc = SEC[e];
    float d0 = sx0[r*3+0]-sx0[cc*3+0];
    float d1 = sx0[r*3+1]-sx0[cc*3+1];
    float d2 = sx0[r*3+2]-sx0[cc*3+2];
    sea[e] = d0*d0 + d1*d1 + d2*d2;
  }
  __syncthreads();

  #pragma unroll 1
  for (int l = 0; l < NL; l++){
    // ---------- phase A ----------
    for (int i = tid; i < 22*68; i += 256) SAF[i] = 0.f;
    if (tid < 68) sdx[tid] = 0.f;
    if (tid < 64){
      SCALf[      tid] = be2[l*64+tid];
      SCALf[ 64 + tid] = bc1[l*64+tid];
      SCALf[128 + tid] = Wa [l*64+tid];
      SCALf[192 + tid] = Wc2[l*64+tid];
      SCALf[256 + tid] = We1[(l*130+128)*64+tid];
      SCALf[320 + tid] = We1[(l*130+129)*64+tid];
    }
    { const short* g2lo = wbt + WTOT + W2T_OFF + l*4096;
      for (int i = tid; i < 512; i += 256){
        int col = i>>3, kc = i&7;
        *(short8v*)(WL2 + col*72 + kc*8) = *(const short8v*)(g2lo + col*64 + kc*8);
      } }
    // node GEMM Y1/Y2 (16 tasks over 4 waves)
    #pragma unroll 1
    for (int task = wv; task < 16; task += 4){
      const int Yv = task>>3, Mt = (task>>2)&1, nt = task&3;
      const int arow = Mt*16 + c, arowR = arow < PB ? arow : PB-1;
      const short* bp = wbt + W1T_OFF + (l*64 + nt*16 + c)*128 + Yv*64;
      const float initv = Yv ? 0.f : be1[l*64 + nt*16 + c];
      f32x4 acc = {initv, initv, initv, initv};
      #pragma unroll
      for (int kt = 0; kt < 2; kt++){
        short8v ah = *(const short8v*)(SHBH + arowR*72 + kt*32 + q*8);
        short8v al = *(const short8v*)(SHBL + arowR*72 + kt*32 + q*8);
        short8v bh = *(const short8v*)(bp + kt*32 + q*8);
        short8v bl = *(const short8v*)(bp + WTOT + kt*32 + q*8);
        acc = MFMA16(ah, bh, acc);
        acc = MFMA16(al, bh, acc);
        acc = MFMA16(ah, bl, acc);
      }
      float* Yp = Yv ? Y2s : Y1s;
      #pragma unroll
      for (int r = 0; r < 4; r++){
        int row = Mt*16 + q*4 + r;
        if (row < PB) Yp[row*68 + nt*16 + c] = acc[r];
      }
    }
    // persistent per-layer register fragments: W2-hi + Wc1-hi
    short8v W2h[2][4], C1h[2][4];
    #pragma unroll
    for (int nt = 0; nt < 4; nt++)
      #pragma unroll
      for (int kt = 0; kt < 2; kt++){
        W2h[kt][nt] = *(const short8v*)(wbt + W2T_OFF  + (l*64+nt*16+c)*64 + kt*32 + q*8);
        C1h[kt][nt] = *(const short8v*)(wbt + WC1T_OFF + (l*64+nt*16+c)*64 + kt*32 + q*8);
      }
    const float bav = ba[l];
    __syncthreads();   // b1

    // ---------- phase B: edge loop ----------
    #pragma unroll 1
    for (int t = wv; t < 29; t += 4){
      const int e0 = t*16, elim = EB - e0;
      const int e = e0 + c;
      const int nr = SER[e], nc = SEC[e];
      const float d0 = sxc[nr*3+0]-sxc[nc*3+0];
      const float d1 = sxc[nr*3+1]-sxc[nc*3+1];
      const float d2 = sxc[nr*3+2]-sxc[nc*3+2];
      const float rad = d0*d0 + d1*d1 + d2*d2;
      const float ea  = sea[e];
      // m1 = silu(Y1[nr] + Y2[nc] + rad*w128 + ea*w129), frag layout
      short8v m1h[2], m1l[2];
      #pragma unroll
      for (int kt = 0; kt < 2; kt++){
        const f32x4 w8a = *(const f32x4*)(SCALf+256 + kt*32 + q*8);
        const f32x4 w8b = *(const f32x4*)(SCALf+256 + kt*32 + q*8 + 4);
        const f32x4 w9a = *(const f32x4*)(SCALf+320 + kt*32 + q*8);
        const f32x4 w9b = *(const f32x4*)(SCALf+320 + kt*32 + q*8 + 4);
        const f32x4 ya = *(const f32x4*)(Y1s + nr*68 + kt*32 + q*8);
        const f32x4 yb = *(const f32x4*)(Y1s + nr*68 + kt*32 + q*8 + 4);
        const f32x4 za = *(const f32x4*)(Y2s + nc*68 + kt*32 + q*8);
        const f32x4 zb = *(const f32x4*)(Y2s + nc*68 + kt*32 + q*8 + 4);
        short8v mh, ml;
        #pragma unroll
        for (int j = 0; j < 4; j++){
          float v = fmaf(rad, w8a[j], fmaf(ea, w9a[j], ya[j]+za[j]));
          short h_, l_; splitT(siluf(v), h_, l_);
          mh[j] = h_; ml[j] = l_;
        }
        #pragma unroll
        for (int j = 0; j < 4; j++){
          float v = fmaf(rad, w8b[j], fmaf(ea, w9b[j], yb[j]+zb[j]));
          short h_, l_; splitT(siluf(v), h_, l_);
          mh[4+j] = h_; ml[4+j] = l_;
        }
        m1h[kt] = mh; m1l[kt] = ml;
      }
      // GEMM2 (swapped, 3-term)
      f32x4 acc2[4];
      #pragma unroll
      for (int nt = 0; nt < 4; nt++)
        acc2[nt] = *(const f32x4*)(SCALf + nt*16 + q*4);
      #pragma unroll
      for (int kt = 0; kt < 2; kt++)
        #pragma unroll
        for (int nt = 0; nt < 4; nt++){
          short8v w2l = *(const short8v*)(WL2 + (nt*16+c)*72 + kt*32 + q*8);
          acc2[nt] = MFMA16(W2h[kt][nt], m1h[kt], acc2[nt]);
          acc2[nt] = MFMA16(w2l,         m1h[kt], acc2[nt]);
          acc2[nt] = MFMA16(W2h[kt][nt], m1l[kt], acc2[nt]);
        }
      // silu + per-lane attention gate
      float m2[4][4]; float gp = 0.f;
      #pragma unroll
      for (int nt = 0; nt < 4; nt++){
        const f32x4 waq = *(const f32x4*)(SCALf+128 + nt*16 + q*4);
        #pragma unroll
        for (int r = 0; r < 4; r++){
          float mv = siluf(acc2[nt][r]); m2[nt][r] = mv;
          gp = fmaf(mv, waq[r], gp);
        }
      }
      gp += __shfl_xor(gp, 16); gp += __shfl_xor(gp, 32);
      const float gate = sigf(gp + bav);
      #pragma unroll
      for (int nt = 0; nt < 4; nt++)
        #pragma unroll
        for (int r = 0; r < 4; r++) m2[nt][r] *= gate;
      // aggregation atomics: 16 distinct nr per 16-lane group -> no same-address serialization
      if (c < elim){
        #pragma unroll
        for (int nt = 0; nt < 4; nt++)
          #pragma unroll
          for (int r = 0; r < 4; r++)
            atomicAdd(&SAF[nr*68 + nt*16 + q*4 + r], m2[nt][r]);
      }
      // mg frags (sigma baked into WC1T prep)
      short8v mgh[2], mgl[2];
      #pragma unroll
      for (int kt = 0; kt < 2; kt++){
        short8v mh, ml;
        #pragma unroll
        for (int j = 0; j < 8; j++){
          short h_, l_; splitT(m2[2*kt + (j>>2)][j&3], h_, l_);
          mh[j] = h_; ml[j] = l_;
        }
        mgh[kt] = mh; mgl[kt] = ml;
      }
      // GEMM3 (swapped, 2-term, Wc1-hi in regs)
      f32x4 acc3[4];
      #pragma unroll
      for (int nt = 0; nt < 4; nt++)
        acc3[nt] = *(const f32x4*)(SCALf+64 + nt*16 + q*4);
      #pragma unroll
      for (int kt = 0; kt < 2; kt++)
        #pragma unroll
        for (int nt = 0; nt < 4; nt++){
          acc3[nt] = MFMA16(C1h[kt][nt], mgh[kt], acc3[nt]);
          acc3[nt] = MFMA16(C1h[kt][nt], mgl[kt], acc3[nt]);
        }
      float pp = 0.f;
      #pragma unroll
      for (int nt = 0; nt < 4; nt++){
        const f32x4 wcq = *(const f32x4*)(SCALf+192 + nt*16 + q*4);
        #pragma unroll
        for (int r = 0; r < 4; r++)
          pp = fmaf(siluf(acc3[nt][r]), wcq[r], pp);
      }
      pp += __shfl_xor(pp, 16); pp += __shfl_xor(pp, 32);
      const float th = tanhff(pp);
      if (q == 0 && c < elim){
        atomicAdd(&sdx[nr*3+0], d0*th);
        atomicAdd(&sdx[nr*3+1], d1*th);
        atomicAdd(&sdx[nr*3+2], d2*th);
      }
    }
    __syncthreads();  // b2

    // ---------- phase C: coord update + node MLP stage 1 ----------
    if (tid < 66) sxc[tid] += sdx[tid];
    {
      short8v An1h[4], An1l[4];
      #pragma unroll
      for (int kt = 0; kt < 4; kt++){
        const short* p = wbt + WN1T_OFF + (l*64 + wv*16 + c)*128 + kt*32 + q*8;
        An1h[kt] = *(const short8v*)p;
        An1l[kt] = *(const short8v*)(p + WTOT);
      }
      float bn1v[4];
      #pragma unroll
      for (int r = 0; r < 4; r++) bn1v[r] = bn1[l*64 + wv*16 + q*4 + r];
      #pragma unroll 1
      for (int tt = 0; tt < 2; tt++){
        const int node = tt*16 + c;
        const int nodeR = node < PB ? node : PB-1;
        f32x4 acc; acc[0]=bn1v[0]; acc[1]=bn1v[1]; acc[2]=bn1v[2]; acc[3]=bn1v[3];
        #pragma unroll
        for (int kt = 0; kt < 2; kt++){
          short8v bh = *(const short8v*)(SHBH + nodeR*72 + kt*32 + q*8);
          short8v bl = *(const short8v*)(SHBL + nodeR*72 + kt*32 + q*8);
          acc = MFMA16(An1h[kt], bh, acc);
          acc = MFMA16(An1l[kt], bh, acc);
          acc = MFMA16(An1h[kt], bl, acc);
        }
        #pragma unroll
        for (int kt = 2; kt < 4; kt++){
          const f32x4 fa = *(const f32x4*)(SAF + nodeR*68 + (kt-2)*32 + q*8);
          const f32x4 fb = *(const f32x4*)(SAF + nodeR*68 + (kt-2)*32 + q*8 + 4);
          short8v bh, bl; short h_, l_;
          #pragma unroll
          for (int j = 0; j < 4; j++){ splitT(fa[j],h_,l_); bh[j]=h_; bl[j]=l_; }
          #pragma unroll
          for (int j = 0; j < 4; j++){ splitT(fb[j],h_,l_); bh[4+j]=h_; bl[4+j]=l_; }
          acc = MFMA16(An1h[kt], bh, acc);
          acc = MFMA16(An1l[kt], bh, acc);
          acc = MFMA16(An1h[kt], bl, acc);
        }
        if (node < PB){
          #pragma unroll
          for (int r = 0; r < 4; r++){
            short hi, lo; splitT(siluf(acc[r]), hi, lo);
            UHI[node*72 + wv*16 + q*4 + r] = hi;
            ULO[node*72 + wv*16 + q*4 + r] = lo;
          }
        }
      }
    }
    __syncthreads();  // b3

    // ---------- phase D: node MLP stage 2 + h residual ----------
    {
      short8v An2h[2], An2l[2];
      #pragma unroll
      for (int kt = 0; kt < 2; kt++){
        const short* p = wbt + WN2T_OFF + (l*64 + wv*16 + c)*64 + kt*32 + q*8;
        An2h[kt] = *(const short8v*)p;
        An2l[kt] = *(const short8v*)(p + WTOT);
      }
      float bn2v[4];
      #pragma unroll
      for (int r = 0; r < 4; r++) bn2v[r] = bn2[l*64 + wv*16 + q*4 + r];
      #pragma unroll 1
      for (int tt = 0; tt < 2; tt++){
        const int node = tt*16 + c;
        const int nodeR = node < PB ? node : PB-1;
        f32x4 acc; acc[0]=bn2v[0]; acc[1]=bn2v[1]; acc[2]=bn2v[2]; acc[3]=bn2v[3];
        #pragma unroll
        for (int kt = 0; kt < 2; kt++){
          short8v uh = *(const short8v*)(UHI + nodeR*72 + kt*32 + q*8);
          short8v ul = *(const short8v*)(ULO + nodeR*72 + kt*32 + q*8);
          acc = MFMA16(An2h[kt], uh, acc);
          acc = MFMA16(An2l[kt], uh, acc);
          acc = MFMA16(An2h[kt], ul, acc);
        }
        if (node < PB){
          #pragma unroll
          for (int r = 0; r < 4; r++){
            int idx = node*72 + wv*16 + q*4 + r;
            float old = bf2f(SHBH[idx]) + bf2f(SHBL[idx]);
            float nh = old + acc[r];
            short hi, lo; splitT(nh, hi, lo);
            SHBH[idx] = hi; SHBL[idx] = lo;
          }
        }
      }
    }
    __syncthreads();  // b4
  }

  if (tid < 3){
    float s = 0.f;
    for (int p = 0; p < PB; p++) s += sxc[p*3+tid] - sx0[p*3+tid];
    smean[tid] = s * (1.f/PB);
  }
  __syncthreads();
  for (int i = tid; i < 66; i += 256)
    out[b*66+i] = sxc[i] - sx0[i] - smean[i%3];
}

extern "C" void kernel_launch(void* const* d_in, const int* in_sizes, int n_in,
                              void* d_out, int out_size, void* d_ws, size_t ws_size,
                              hipStream_t stream){
  const float* t    = (const float*)d_in[0];
  const float* x    = (const float*)d_in[1];
  const float* h0   = (const float*)d_in[2];
  const float* embW = (const float*)d_in[3];
  const float* embB = (const float*)d_in[4];
  const float* We1  = (const float*)d_in[5];
  const float* be1  = (const float*)d_in[6];
  const float* We2  = (const float*)d_in[7];
  const float* be2  = (const float*)d_in[8];
  const float* Wa   = (const float*)d_in[9];
  const float* ba   = (const float*)d_in[10];
  const float* Wc1  = (const float*)d_in[11];
  const float* bc1  = (const float*)d_in[12];
  const float* Wc2  = (const float*)d_in[13];
  const float* Wn1  = (const float*)d_in[14];
  const float* bn1  = (const float*)d_in[15];
  const float* Wn2  = (const float*)d_in[16];
  const float* bn2  = (const float*)d_in[17];
  const int* rows   = (const int*)d_in[18];
  const int* cols   = (const int*)d_in[19];
  short* wbt = (short*)d_ws;

  hipLaunchKernelGGL(prep_weights, dim3((WTOT+255)/256), dim3(256), 0, stream,
                     We1, We2, Wc1, Wn1, Wn2, wbt);
  hipLaunchKernelGGL(egnn4, dim3(2048), dim3(256), 0, stream,
                     t, x, h0, embW, embB, We1, be1, be2, Wa, ba, bc1, Wc2,
                     bn1, bn2, rows, cols, (const short*)wbt, (float*)d_out);
}